// Round 8
// baseline (345.943 us; speedup 1.0000x reference)
//
#include <hip/hip_runtime.h>
#include <hip/hip_cooperative_groups.h>

namespace cg = cooperative_groups;

// VectorQuantizer: N=262144 rows, D=64 dims, K=512 codewords, fp32.
// out layout (floats): [0,N) idx ; [N, N+N*D) quantized_st ; [N+N*D] vq_loss
//
// CORRECTNESS MODEL (verified R2-R5, absmax 0): reference fp32 bit pattern is
//   d2 = fl(fl(x2 - fl(2*m)) + w2), x2/w2 numpy pairwise-8 order, m = sequential
//   FMA chain d ascending (BLAS), argmin strict < (first-min tie-break).
// Two-phase: MFMA approx scores (bf16 hi/mid splits of -2w, 3 terms) +
// exact-chain recheck of rows with top-2 gap < margin.
//
// R12: dispatch-count attack (5 -> 3). Non-gemm time (~191us) is unexplained
// by kernel work models (~105us) => fixed per-dispatch overhead suspected.
// (a) prep folded into vq_gemm: A-frags + w2p3 built in-register per block,
//     SAME op order on same values => scores bit-identical; tables gone.
// (b) merge+recheck fused into ONE cooperative kernel (512x256, grid.sync
//     between phases; capacity 1024 blocks @32KB LDS => 2x margin). Per-row
//     merge algebra identical; recheck = 2 cw/thread in 2 passes, identical
//     per-(row,cw) chains + same lowest-index argmin => out_idx bit-identical.
// (c) epilogue untouched (loss bit-structure frozen).
// (d) gemm XCD pairing swizzle: blocks b,b+8 = the two halves of one row-tile.
#define NROWS 262144
#define DDIM  64
#define KCB   512

// key = (fp32 bits of s''=w2+3-2*dot) << 9 | cw ; s'' in [2.8,3.2] => one
// exponent octave => bits monotone. 1 key unit = ulp(3)/512 ; MARGKEY = 3<<17
// => 768 ulps = 1.83e-4 >= 2x worst-case |approx - ref| bound (~9.1e-5).
#define MARGKEY (3u << 17)

// ws layout (bytes) — w2p3/whi/wmid regions retired (tables folded into gemm)
#define WS_CNT   0
#define WS_LIST  135168

typedef __attribute__((ext_vector_type(8))) short short8;
typedef __attribute__((ext_vector_type(4))) float floatx4;
typedef __attribute__((ext_vector_type(16))) float floatx16;
typedef __attribute__((ext_vector_type(2))) unsigned int uintx2;

#if defined(__has_builtin)
#if __has_builtin(__builtin_amdgcn_permlane32_swap)
#define VQ_PLSWAP 1
#endif
#endif

__device__ __forceinline__ unsigned umin2(unsigned a, unsigned b) { return a < b ? a : b; }
__device__ __forceinline__ unsigned umax2(unsigned a, unsigned b) { return a > b ? a : b; }

// numpy FLOAT_pairwise_sum order for n=64 over terms fl(a[i]*a[i])  [R2-verified]
__device__ __forceinline__ float np_sumsq64(const float* a) {
    float r[8];
#pragma unroll
    for (int j = 0; j < 8; ++j) r[j] = __fmul_rn(a[j], a[j]);
#pragma unroll
    for (int i = 8; i < 64; i += 8) {
#pragma unroll
        for (int j = 0; j < 8; ++j)
            r[j] = __fadd_rn(r[j], __fmul_rn(a[i + j], a[i + j]));
    }
    return __fadd_rn(__fadd_rn(__fadd_rn(r[0], r[1]), __fadd_rn(r[2], r[3])),
                     __fadd_rn(__fadd_rn(r[4], r[5]), __fadd_rn(r[6], r[7])));
}

// streaming variant (register-light, identical op order on a contiguous row)
__device__ __forceinline__ float np_sumsq64_stream(const float* a) {
    const float4* p = (const float4*)a;
    float4 v0 = p[0], v1 = p[1];
    float r[8];
    r[0] = __fmul_rn(v0.x, v0.x); r[1] = __fmul_rn(v0.y, v0.y);
    r[2] = __fmul_rn(v0.z, v0.z); r[3] = __fmul_rn(v0.w, v0.w);
    r[4] = __fmul_rn(v1.x, v1.x); r[5] = __fmul_rn(v1.y, v1.y);
    r[6] = __fmul_rn(v1.z, v1.z); r[7] = __fmul_rn(v1.w, v1.w);
#pragma unroll
    for (int i = 1; i < 8; ++i) {
        float4 u0 = p[2 * i], u1 = p[2 * i + 1];
        r[0] = __fadd_rn(r[0], __fmul_rn(u0.x, u0.x));
        r[1] = __fadd_rn(r[1], __fmul_rn(u0.y, u0.y));
        r[2] = __fadd_rn(r[2], __fmul_rn(u0.z, u0.z));
        r[3] = __fadd_rn(r[3], __fmul_rn(u0.w, u0.w));
        r[4] = __fadd_rn(r[4], __fmul_rn(u1.x, u1.x));
        r[5] = __fadd_rn(r[5], __fmul_rn(u1.y, u1.y));
        r[6] = __fadd_rn(r[6], __fmul_rn(u1.z, u1.z));
        r[7] = __fadd_rn(r[7], __fmul_rn(u1.w, u1.w));
    }
    return __fadd_rn(__fadd_rn(__fadd_rn(r[0], r[1]), __fadd_rn(r[2], r[3])),
                     __fadd_rn(__fadd_rn(r[4], r[5]), __fadd_rn(r[6], r[7])));
}

// pack two fp32 into bf16-truncate hi dword + residual-bf16 mid dword
__device__ __forceinline__ void split2(float e0, float e1, unsigned& hid, unsigned& mid) {
    unsigned u0 = __float_as_uint(e0), u1 = __float_as_uint(e1);
    float r0 = __fsub_rn(e0, __uint_as_float(u0 & 0xFFFF0000u));  // exact
    float r1 = __fsub_rn(e1, __uint_as_float(u1 & 0xFFFF0000u));  // exact
    hid = (u0 >> 16) | (u1 & 0xFFFF0000u);
    mid = (__float_as_uint(r0) >> 16) | (__float_as_uint(r1) & 0xFFFF0000u);
}

__device__ __forceinline__ void split4(float4 v, uint2& h, uint2& m) {
    unsigned h0, m0, h1, m1;
    split2(v.x, v.y, h0, m0);
    split2(v.z, v.w, h1, m1);
    h = make_uint2(h0, h1);
    m = make_uint2(m0, m1);
}

// 8 w-values (two float4) -> hi/mid short8 frags of v=-2*w (exact pow2 scale);
// bit-identical to the retired prep tables (same split2 on same values).
__device__ __forceinline__ void build8n2(float4 a, float4 b, short8& hi, short8& mi) {
    union { unsigned d[4]; short8 s; } H, M;
    split2(__fmul_rn(-2.0f, a.x), __fmul_rn(-2.0f, a.y), H.d[0], M.d[0]);
    split2(__fmul_rn(-2.0f, a.z), __fmul_rn(-2.0f, a.w), H.d[1], M.d[1]);
    split2(__fmul_rn(-2.0f, b.x), __fmul_rn(-2.0f, b.y), H.d[2], M.d[2]);
    split2(__fmul_rn(-2.0f, b.z), __fmul_rn(-2.0f, b.w), H.d[3], M.d[3]);
    hi = H.s; mi = M.s;
}

// xor-32 merge of (min1,min2) pairs across lane halves.
__device__ __forceinline__ void merge32(unsigned& m1, unsigned& m2) {
#ifdef VQ_PLSWAP
    uintx2 s1 = __builtin_amdgcn_permlane32_swap(m1, m1, false, false);
    uintx2 s2 = __builtin_amdgcn_permlane32_swap(m2, m2, false, false);
    m2 = umin2(umin2(s2[0], s2[1]), umax2(s1[0], s1[1]));
    m1 = umin2(s1[0], s1[1]);
#else
    unsigned o1 = __shfl_xor((int)m1, 32);
    unsigned o2 = __shfl_xor((int)m2, 32);
    m2 = umin2(umin2(m2, o2), umax2(m1, o1));
    m1 = umin2(m1, o1);
#endif
}

// top-2 (min1,min2) of 16 keys, balanced tree
__device__ __forceinline__ void top2_16(const unsigned* k, unsigned& m1, unsigned& m2) {
    unsigned lo[8], hi[8];
#pragma unroll
    for (int i = 0; i < 8; ++i) {
        lo[i] = umin2(k[2 * i], k[2 * i + 1]);
        hi[i] = umax2(k[2 * i], k[2 * i + 1]);
    }
#pragma unroll
    for (int s = 4; s >= 1; s >>= 1) {
#pragma unroll
        for (int i = 0; i < s; ++i) {
            unsigned l = umin2(lo[i], lo[i + s]);
            unsigned h = umin2(umax2(lo[i], lo[i + s]), umin2(hi[i], hi[i + s]));
            lo[i] = l; hi[i] = h;
        }
    }
    m1 = lo[0]; m2 = hi[0];
}

// ---- phase-1: 2048 blocks of 256 thr = 4 waves. Block = (row-tile of 256) x
// (codebook half of 256 cw). Prep folded in: A-frags + w2p3s built in-register
// from w (bit-identical values). XCD pairing: blocks b and b+8 are the two
// halves of one row-tile (assuming xcd = blockIdx%8) -> shared L2 for x.
// Per-wave math identical to R9/R11 (measured 55.7-57us, MfmaUtil ~37%). ----
__launch_bounds__(256, 4)
__global__ void vq_gemm(const float* __restrict__ x,
                        const float* __restrict__ w,
                        uint2* __restrict__ mmg,
                        unsigned* __restrict__ cnt,
                        float* __restrict__ loss) {
    const int tid = threadIdx.x;
    const int bid = blockIdx.x;
    if (bid == 0 && tid == 0) { *cnt = 0u; *loss = 0.0f; }

    const int wave = tid >> 6, lane = tid & 63;
    const int row32 = lane & 31;   // A: cw-in-tile; B: x-row; C: x-row (col)
    const int khalf = lane >> 5;   // A/B: k-subwindow; C: cw-subset offset/4
    // pairing swizzle: b and b+8 share (unit), differ in (half), same XCD
    const int half = (bid >> 3) & 1;
    const int unit = (bid & 7) | ((bid >> 4) << 3);
    const int r0 = unit * 256;

    __shared__ float w2p3s[256];                         // 1 KB (this half)
    __shared__ __align__(16) unsigned sbh[2][32 * 36];   // B hi tiles (9 KB)
    __shared__ __align__(16) unsigned sbm[2][32 * 36];   // B mid tiles (9 KB)
    __shared__ uint2 mm[4][8][32];                       // per-wave min1/min2 (8 KB)

    // w2p3 in-register (streaming, numpy order => bit-identical to old prep)
    w2p3s[tid] = __fadd_rn(np_sumsq64_stream(w + (size_t)(half * 256 + tid) * DDIM), 3.0f);

    // A-frags in-register: tile tt (32 cw), k-step t (16 dims). Lane holds
    // cw = half*256 + wave*64 + tt*32 + row32, dims t*16 + khalf*8 + j.
    short8 ah[2][4], am[2][4];
#pragma unroll
    for (int tt = 0; tt < 2; ++tt) {
        const size_t cw = (size_t)(half * 256 + wave * 64 + tt * 32 + row32);
#pragma unroll
        for (int t = 0; t < 4; ++t) {
            const float* wp = w + cw * 64 + t * 16 + khalf * 8;
            float4 a = *(const float4*)wp;
            float4 b = *(const float4*)(wp + 4);
            build8n2(a, b, ah[tt][t], am[tt][t]);
        }
    }

    // staging: 256 threads stage 32 rows x 16 float4: thread owns rows srow,
    // srow+16 at float4-col sc4.
    const int srow = tid >> 4, sc4 = tid & 15;
    {
        float4 v0 = *(const float4*)(x + (size_t)(r0 + srow) * DDIM + 4 * sc4);
        float4 v1 = *(const float4*)(x + (size_t)(r0 + srow + 16) * DDIM + 4 * sc4);
        uint2 h, m;
        split4(v0, h, m);
        *(uint2*)&sbh[0][srow * 36 + 2 * sc4] = h;
        *(uint2*)&sbm[0][srow * 36 + 2 * sc4] = m;
        split4(v1, h, m);
        *(uint2*)&sbh[0][(srow + 16) * 36 + 2 * sc4] = h;
        *(uint2*)&sbm[0][(srow + 16) * 36 + 2 * sc4] = m;
    }
    __syncthreads();

    // key cw base for this lane's C-subset: + tt*32 + (reg&3)+8*(reg>>2)
    const unsigned cwk = (unsigned)(half * 256 + wave * 64 + 4 * khalf);

    for (int it = 0; it < 8; ++it) {
        const int p = it & 1;
        float4 pre0, pre1;
        if (it < 7) {
            pre0 = *(const float4*)(x + (size_t)(r0 + (it + 1) * 32 + srow) * DDIM + 4 * sc4);
            pre1 = *(const float4*)(x + (size_t)(r0 + (it + 1) * 32 + srow + 16) * DDIM + 4 * sc4);
        }

        // B-frags: row = row32, k-step t: dwords t*8 + khalf*4 .. +3
        short8 bh[4], bm[4];
#pragma unroll
        for (int t = 0; t < 4; ++t) {
            bh[t] = *(const short8*)&sbh[p][row32 * 36 + t * 8 + khalf * 4];
            bm[t] = *(const short8*)&sbm[p][row32 * 36 + t * 8 + khalf * 4];
        }

        unsigned r1t[2], r2t[2];
#pragma unroll
        for (int tt = 0; tt < 2; ++tt) {
            // acc init: reg 4g+i -> m = i + 8g + 4*khalf (contiguous quads)
            floatx16 acc;
            const int wb = wave * 64 + tt * 32 + 4 * khalf;
#pragma unroll
            for (int g = 0; g < 4; ++g) {
                floatx4 v = *(const floatx4*)&w2p3s[wb + 8 * g];
                acc[4 * g + 0] = v[0]; acc[4 * g + 1] = v[1];
                acc[4 * g + 2] = v[2]; acc[4 * g + 3] = v[3];
            }
#pragma unroll
            for (int t = 0; t < 4; ++t) {
                acc = __builtin_amdgcn_mfma_f32_32x32x16_bf16(ah[tt][t], bh[t], acc, 0, 0, 0);
                acc = __builtin_amdgcn_mfma_f32_32x32x16_bf16(ah[tt][t], bm[t], acc, 0, 0, 0);
                acc = __builtin_amdgcn_mfma_f32_32x32x16_bf16(am[tt][t], bh[t], acc, 0, 0, 0);
            }
            // keys for this tile's 16 lane-local cw
            unsigned keys[16];
#pragma unroll
            for (int r = 0; r < 16; ++r) {
                const unsigned moff = (unsigned)((r & 3) + 8 * (r >> 2) + tt * 32);
                keys[r] = (__float_as_uint(acc[r]) << 9) + cwk + moff;
            }
            top2_16(keys, r1t[tt], r2t[tt]);
        }
        unsigned m1 = umin2(r1t[0], r1t[1]);
        unsigned m2 = umin2(umax2(r1t[0], r1t[1]), umin2(r2t[0], r2t[1]));
        merge32(m1, m2);   // combine complementary cw subsets (same x-row)
        if (lane < 32) mm[wave][it][row32] = make_uint2(m1, m2);

        if (it < 7) {
            uint2 h, m;
            split4(pre0, h, m);
            *(uint2*)&sbh[p ^ 1][srow * 36 + 2 * sc4] = h;
            *(uint2*)&sbm[p ^ 1][srow * 36 + 2 * sc4] = m;
            split4(pre1, h, m);
            *(uint2*)&sbh[p ^ 1][(srow + 16) * 36 + 2 * sc4] = h;
            *(uint2*)&sbm[p ^ 1][(srow + 16) * 36 + 2 * sc4] = m;
        }
        __syncthreads();
    }

    // deferred cross-wave merge: thread tid owns row r0+tid (it=tid>>5, rl=tid&31)
    unsigned a1 = 0xFFFFFFFFu, a2 = 0xFFFFFFFFu;
#pragma unroll
    for (int wv = 0; wv < 4; ++wv) {
        uint2 v = mm[wv][tid >> 5][tid & 31];
        a2 = umin2(umin2(a2, v.y), umax2(a1, v.x));
        a1 = umin2(a1, v.x);
    }
    mmg[(size_t)half * NROWS + (r0 + tid)] = make_uint2(a1, a2);
}

// ---- cooperative tail: phase M (merge halves -> idx + flag list) ;
// grid.sync ; phase R (exact recheck of flagged rows). 512 blocks x 256 thr,
// ~32KB LDS => 4 blocks/CU capacity (1024) >= 512, 2x margin. ----
__launch_bounds__(256, 4)
__global__ void vq_tail(const float* __restrict__ x,
                        const float* __restrict__ w,
                        const uint2* __restrict__ mmg,
                        float* __restrict__ out_idx,
                        unsigned* __restrict__ cnt,
                        unsigned* __restrict__ list, int listcap) {
    cg::grid_group grid = cg::this_grid();
    const int tid = threadIdx.x;
    const int bid = blockIdx.x;
    const int lane = tid & 63;

    // ---- phase M: rows bid*512 + c*256 + tid (same per-row algebra as R11) --
#pragma unroll
    for (int c = 0; c < 2; ++c) {
        const int row = bid * 512 + c * 256 + tid;
        uint2 v0 = mmg[row];
        uint2 v1 = mmg[(size_t)NROWS + row];
        unsigned a1 = umin2(v0.x, v1.x);
        unsigned a2 = umin2(umax2(v0.x, v1.x), umin2(v0.y, v1.y));
        out_idx[row] = (float)(a1 & 511u);
        bool flag = (a2 - a1 < MARGKEY);
        unsigned long long mask = __ballot(flag);
        int nw = __popcll(mask);
        unsigned base = 0;
        if (lane == 0 && nw) base = atomicAdd(cnt, (unsigned)nw);
        base = (unsigned)__shfl((int)base, 0);
        if (flag) {
            unsigned pos = base + (unsigned)__popcll(mask & ((1ull << lane) - 1ull));
            if ((int)pos < listcap) list[pos] = (unsigned)row;
        }
    }
    __threadfence();
    grid.sync();

    // ---- phase R: exact recheck (R4-verified math; 2 cw per thread now) ----
    unsigned total = *cnt;
    if (total > (unsigned)listcap) total = (unsigned)listcap;
    const unsigned nb = (total + 15) >> 4;

    __shared__ float d2tile[16][KCB];   // 32 KB
    __shared__ int rowbuf[16];
    __shared__ float x2buf[16];

    for (unsigned batch = (unsigned)bid; batch < nb; batch += 512u) {
        if (tid < 16) {
            unsigned li = batch * 16 + (unsigned)tid;
            rowbuf[tid] = (li < total) ? (int)list[li] : -1;
        }
        __syncthreads();

        // x2 per row: 8 threads/row, numpy pairwise-8 order + exact shfl tree
        if (tid < 128) {
            const int rl = tid >> 3, j = tid & 7;
            int row = rowbuf[rl]; if (row < 0) row = 0;
            const float* xr = x + (size_t)row * DDIM;
            float a0 = xr[j];
            float r = __fmul_rn(a0, a0);
#pragma unroll
            for (int i = 1; i < 8; ++i) {
                float ai = xr[8 * i + j];
                r = __fadd_rn(r, __fmul_rn(ai, ai));
            }
            float s1 = __fadd_rn(r,  __shfl_xor(r, 1));
            float s2 = __fadd_rn(s1, __shfl_xor(s1, 2));
            float s4 = __fadd_rn(s2, __shfl_xor(s2, 4));
            if (j == 0) x2buf[rl] = s4;
        }
        __syncthreads();

        // exact chains: thread owns cw (pass*256 + tid); per-(row,cw) chain
        // order identical to R4/R11 => d2 bits identical
#pragma unroll 1
        for (int pass = 0; pass < 2; ++pass) {
            const int mycw = pass * 256 + tid;
            float wl[64];
            {
                const float4* wp = (const float4*)(w + (size_t)mycw * DDIM);
#pragma unroll
                for (int j = 0; j < 16; ++j) {
                    float4 v = wp[j];
                    wl[4 * j + 0] = v.x; wl[4 * j + 1] = v.y;
                    wl[4 * j + 2] = v.z; wl[4 * j + 3] = v.w;
                }
            }
            const float w2l = np_sumsq64(wl);

            for (int g = 0; g < 16; g += 4) {
                int ra = rowbuf[g + 0]; if (ra < 0) ra = 0;
                int rb = rowbuf[g + 1]; if (rb < 0) rb = 0;
                int rc = rowbuf[g + 2]; if (rc < 0) rc = 0;
                int rd = rowbuf[g + 3]; if (rd < 0) rd = 0;
                const float* xr0 = x + (size_t)ra * DDIM;
                const float* xr1 = x + (size_t)rb * DDIM;
                const float* xr2 = x + (size_t)rc * DDIM;
                const float* xr3 = x + (size_t)rd * DDIM;
                float m0 = 0.f, m1 = 0.f, m2 = 0.f, m3 = 0.f;
#pragma unroll
                for (int jb = 0; jb < 16; ++jb) {
                    float4 a0 = *(const float4*)(xr0 + 4 * jb);
                    float4 a1 = *(const float4*)(xr1 + 4 * jb);
                    float4 a2 = *(const float4*)(xr2 + 4 * jb);
                    float4 a3 = *(const float4*)(xr3 + 4 * jb);
                    m0 = __fmaf_rn(a0.x, wl[4 * jb + 0], m0);
                    m0 = __fmaf_rn(a0.y, wl[4 * jb + 1], m0);
                    m0 = __fmaf_rn(a0.z, wl[4 * jb + 2], m0);
                    m0 = __fmaf_rn(a0.w, wl[4 * jb + 3], m0);
                    m1 = __fmaf_rn(a1.x, wl[4 * jb + 0], m1);
                    m1 = __fmaf_rn(a1.y, wl[4 * jb + 1], m1);
                    m1 = __fmaf_rn(a1.z, wl[4 * jb + 2], m1);
                    m1 = __fmaf_rn(a1.w, wl[4 * jb + 3], m1);
                    m2 = __fmaf_rn(a2.x, wl[4 * jb + 0], m2);
                    m2 = __fmaf_rn(a2.y, wl[4 * jb + 1], m2);
                    m2 = __fmaf_rn(a2.z, wl[4 * jb + 2], m2);
                    m2 = __fmaf_rn(a2.w, wl[4 * jb + 3], m2);
                    m3 = __fmaf_rn(a3.x, wl[4 * jb + 0], m3);
                    m3 = __fmaf_rn(a3.y, wl[4 * jb + 1], m3);
                    m3 = __fmaf_rn(a3.z, wl[4 * jb + 2], m3);
                    m3 = __fmaf_rn(a3.w, wl[4 * jb + 3], m3);
                }
                float X0 = x2buf[g + 0], X1 = x2buf[g + 1];
                float X2 = x2buf[g + 2], X3 = x2buf[g + 3];
                d2tile[g + 0][mycw] = __fadd_rn(__fsub_rn(X0, __fmul_rn(2.0f, m0)), w2l);
                d2tile[g + 1][mycw] = __fadd_rn(__fsub_rn(X1, __fmul_rn(2.0f, m1)), w2l);
                d2tile[g + 2][mycw] = __fadd_rn(__fsub_rn(X2, __fmul_rn(2.0f, m2)), w2l);
                d2tile[g + 3][mycw] = __fadd_rn(__fsub_rn(X3, __fmul_rn(2.0f, m3)), w2l);
            }
        }
        __syncthreads();

        // exact argmin per row: 16 threads/row, strict < ascending scan +
        // lower-index tie-break tree => lowest-index-of-min (same semantics)
        {
            const int rl  = tid >> 4;
            const int sub = tid & 15;
            float bv = d2tile[rl][sub];
            int   bi = sub;
#pragma unroll
            for (int i = 1; i < 32; ++i) {
                int cc = sub + 16 * i;
                float v = d2tile[rl][cc];
                if (v < bv) { bv = v; bi = cc; }
            }
#pragma unroll
            for (int s = 1; s < 16; s <<= 1) {
                float ov = __shfl_xor(bv, s);
                int   oi = __shfl_xor(bi, s);
                if (ov < bv || (ov == bv && oi < bi)) { bv = ov; bi = oi; }
            }
            if (sub == 0 && rowbuf[rl] >= 0) out_idx[rowbuf[rl]] = (float)bi;
        }
        __syncthreads();
    }
}

// ---- epilogue: gather codeword, quantized_st = fl(x + fl(q-x)), loss.
// UNCHANGED from R11 (loss partial-sum structure is bit-critical). ----
__launch_bounds__(256)
__global__ void vq_epilogue(const float* __restrict__ x,
                            const float* __restrict__ w,
                            const float* __restrict__ out_idx_f,
                            float* __restrict__ out_q,
                            float* __restrict__ out_loss) {
    const int tid = threadIdx.x;
    const int r0  = blockIdx.x * 256;
    const int bidx = (int)out_idx_f[r0 + tid];   // coalesced idx load
    const float4* wq = (const float4*)(w + (size_t)bidx * DDIM);

    __shared__ float tile[128][65];   // 33.3 KB, +1 pad => conflict-minimal
    __shared__ float red[4];

    float ls = 0.0f;
#pragma unroll
    for (int ph = 0; ph < 2; ++ph) {
        const int rb = r0 + ph * 128;
        __syncthreads();   // prior store-phase reads done before overwrite
        // coalesced load: 128 rows x 16 float4 = 2048 float4; 8 per thread
#pragma unroll
        for (int i = 0; i < 8; ++i) {
            const int li = tid + 256 * i;            // linear float4 index
            const int row = li >> 4, c4 = li & 15;
            float4 v = *(const float4*)(x + (size_t)(rb + row) * DDIM + 4 * c4);
            *(float4*)&tile[row][4 * c4] = v;
        }
        __syncthreads();
        // compute: threads ph*128..ph*128+127 own their row (tid->row kept)
        if ((tid >> 7) == ph) {
            const int lr = tid & 127;
#pragma unroll
            for (int j = 0; j < 16; ++j) {
                float4 xv = *(const float4*)&tile[lr][4 * j];
                float4 wv = wq[j];
                float e0 = __fsub_rn(wv.x, xv.x), e1 = __fsub_rn(wv.y, xv.y);
                float e2 = __fsub_rn(wv.z, xv.z), e3 = __fsub_rn(wv.w, xv.w);
                ls = fmaf(e0, e0, ls); ls = fmaf(e1, e1, ls);
                ls = fmaf(e2, e2, ls); ls = fmaf(e3, e3, ls);
                float4 q;
                q.x = __fadd_rn(xv.x, e0); q.y = __fadd_rn(xv.y, e1);
                q.z = __fadd_rn(xv.z, e2); q.w = __fadd_rn(xv.w, e3);
                *(float4*)&tile[lr][4 * j] = q;   // own-row slot, in place
            }
        }
        __syncthreads();
        // coalesced store of q from LDS
#pragma unroll
        for (int i = 0; i < 8; ++i) {
            const int li = tid + 256 * i;
            const int row = li >> 4, c4 = li & 15;
            float4 qv = *(const float4*)&tile[row][4 * c4];
            *(float4*)(out_q + (size_t)(rb + row) * DDIM + 4 * c4) = qv;
        }
    }

#pragma unroll
    for (int off = 32; off > 0; off >>= 1) ls += __shfl_down(ls, off);
    const int lane = tid & 63;
    const int wid  = tid >> 6;
    if (lane == 0) red[wid] = ls;
    __syncthreads();
    if (tid == 0) {
        float t = (red[0] + red[1]) + (red[2] + red[3]);
        atomicAdd(out_loss, t * (1.25f / (float)(NROWS * DDIM)));  // (1+BETA)*mean
    }
}

extern "C" void kernel_launch(void* const* d_in, const int* in_sizes, int n_in,
                              void* d_out, int out_size, void* d_ws, size_t ws_size,
                              hipStream_t stream) {
    const float* x = (const float*)d_in[0];   // encoding [N, 64]
    const float* w = (const float*)d_in[1];   // weight   [512, 64]

    float* out      = (float*)d_out;
    float* out_idx  = out;
    float* out_q    = out + (size_t)NROWS;
    float* out_loss = out + (size_t)NROWS + (size_t)NROWS * DDIM;

    // half-results parked in the out_q region (4 MB of 64 MB); epilogue
    // rewrites out_q fully AFTER vq_tail's last read of mmg.
    uint2* mmg = (uint2*)out_q;

    char* ws = (char*)d_ws;
    unsigned* cnt  = (unsigned*)(ws + WS_CNT);
    unsigned* list = (unsigned*)(ws + WS_LIST);
    long cap = ((long)ws_size - WS_LIST) / 4;
    int listcap = cap > 0 ? (cap > NROWS ? NROWS : (int)cap) : 0;

    vq_gemm<<<2048, 256, 0, stream>>>(x, w, mmg, cnt, out_loss);

    {
        const float* xx = x; const float* ww = w;
        const uint2* mm = mmg; float* oi = out_idx;
        unsigned* cp = cnt; unsigned* lp = list; int lc = listcap;
        void* args[] = { &xx, &ww, &mm, &oi, &cp, &lp, &lc };
        hipLaunchCooperativeKernel((const void*)vq_tail, dim3(512), dim3(256),
                                   args, 0, stream);
    }

    vq_epilogue<<<NROWS / 256, 256, 0, stream>>>(x, w, out_idx, out_q, out_loss);
}

// Round 9
// 312.532 us; speedup vs baseline: 1.1069x; 1.1069x over previous
//
#include <hip/hip_runtime.h>
#include <hip/hip_cooperative_groups.h>

namespace cg = cooperative_groups;

// VectorQuantizer: N=262144 rows, D=64 dims, K=512 codewords, fp32.
// out layout (floats): [0,N) idx ; [N, N+N*D) quantized_st ; [N+N*D] vq_loss
//
// CORRECTNESS MODEL (verified R2-R5, absmax 0): reference fp32 bit pattern is
//   d2 = fl(fl(x2 - fl(2*m)) + w2), x2/w2 numpy pairwise-8 order, m = sequential
//   FMA chain d ascending (BLAS), argmin strict < (first-min tie-break).
// Two-phase: MFMA approx scores (bf16 hi/mid splits of -2w, 3 terms) +
// exact-chain recheck of rows with top-2 gap < margin.
//
// R13: fix R12's tail regression (145us; VGPR=64 => wl[64] spilled to scratch,
// scratch loads on the FMA critical path). Tail rebuilt as cooperative
// 256 blocks x 512 threads: phase M (merge, 2 rows/thread) -> grid.sync ->
// phase R = VERBATIM R11 recheck body (1 cw/thread, wl loaded ONCE,
// launch_bounds(512,4) — the config that measurably did not spill).
// vq_gemm keeps folded prep (absmax-0 verified) but reverts the XCD swizzle
// to the R11 mapping (removes the one untested gemm variable). Epilogue
// unchanged. 3 dispatches total.
#define NROWS 262144
#define DDIM  64
#define KCB   512

// key = (fp32 bits of s''=w2+3-2*dot) << 9 | cw ; s'' in [2.8,3.2] => one
// exponent octave => bits monotone. 1 key unit = ulp(3)/512 ; MARGKEY = 3<<17
// => 768 ulps = 1.83e-4 >= 2x worst-case |approx - ref| bound (~9.1e-5).
#define MARGKEY (3u << 17)

// ws layout (bytes)
#define WS_CNT   0
#define WS_LIST  135168

typedef __attribute__((ext_vector_type(8))) short short8;
typedef __attribute__((ext_vector_type(4))) float floatx4;
typedef __attribute__((ext_vector_type(16))) float floatx16;
typedef __attribute__((ext_vector_type(2))) unsigned int uintx2;

#if defined(__has_builtin)
#if __has_builtin(__builtin_amdgcn_permlane32_swap)
#define VQ_PLSWAP 1
#endif
#endif

__device__ __forceinline__ unsigned umin2(unsigned a, unsigned b) { return a < b ? a : b; }
__device__ __forceinline__ unsigned umax2(unsigned a, unsigned b) { return a > b ? a : b; }

// numpy FLOAT_pairwise_sum order for n=64 over terms fl(a[i]*a[i])  [R2-verified]
__device__ __forceinline__ float np_sumsq64(const float* a) {
    float r[8];
#pragma unroll
    for (int j = 0; j < 8; ++j) r[j] = __fmul_rn(a[j], a[j]);
#pragma unroll
    for (int i = 8; i < 64; i += 8) {
#pragma unroll
        for (int j = 0; j < 8; ++j)
            r[j] = __fadd_rn(r[j], __fmul_rn(a[i + j], a[i + j]));
    }
    return __fadd_rn(__fadd_rn(__fadd_rn(r[0], r[1]), __fadd_rn(r[2], r[3])),
                     __fadd_rn(__fadd_rn(r[4], r[5]), __fadd_rn(r[6], r[7])));
}

// streaming variant (register-light, identical op order on a contiguous row)
__device__ __forceinline__ float np_sumsq64_stream(const float* a) {
    const float4* p = (const float4*)a;
    float4 v0 = p[0], v1 = p[1];
    float r[8];
    r[0] = __fmul_rn(v0.x, v0.x); r[1] = __fmul_rn(v0.y, v0.y);
    r[2] = __fmul_rn(v0.z, v0.z); r[3] = __fmul_rn(v0.w, v0.w);
    r[4] = __fmul_rn(v1.x, v1.x); r[5] = __fmul_rn(v1.y, v1.y);
    r[6] = __fmul_rn(v1.z, v1.z); r[7] = __fmul_rn(v1.w, v1.w);
#pragma unroll
    for (int i = 1; i < 8; ++i) {
        float4 u0 = p[2 * i], u1 = p[2 * i + 1];
        r[0] = __fadd_rn(r[0], __fmul_rn(u0.x, u0.x));
        r[1] = __fadd_rn(r[1], __fmul_rn(u0.y, u0.y));
        r[2] = __fadd_rn(r[2], __fmul_rn(u0.z, u0.z));
        r[3] = __fadd_rn(r[3], __fmul_rn(u0.w, u0.w));
        r[4] = __fadd_rn(r[4], __fmul_rn(u1.x, u1.x));
        r[5] = __fadd_rn(r[5], __fmul_rn(u1.y, u1.y));
        r[6] = __fadd_rn(r[6], __fmul_rn(u1.z, u1.z));
        r[7] = __fadd_rn(r[7], __fmul_rn(u1.w, u1.w));
    }
    return __fadd_rn(__fadd_rn(__fadd_rn(r[0], r[1]), __fadd_rn(r[2], r[3])),
                     __fadd_rn(__fadd_rn(r[4], r[5]), __fadd_rn(r[6], r[7])));
}

// pack two fp32 into bf16-truncate hi dword + residual-bf16 mid dword
__device__ __forceinline__ void split2(float e0, float e1, unsigned& hid, unsigned& mid) {
    unsigned u0 = __float_as_uint(e0), u1 = __float_as_uint(e1);
    float r0 = __fsub_rn(e0, __uint_as_float(u0 & 0xFFFF0000u));  // exact
    float r1 = __fsub_rn(e1, __uint_as_float(u1 & 0xFFFF0000u));  // exact
    hid = (u0 >> 16) | (u1 & 0xFFFF0000u);
    mid = (__float_as_uint(r0) >> 16) | (__float_as_uint(r1) & 0xFFFF0000u);
}

__device__ __forceinline__ void split4(float4 v, uint2& h, uint2& m) {
    unsigned h0, m0, h1, m1;
    split2(v.x, v.y, h0, m0);
    split2(v.z, v.w, h1, m1);
    h = make_uint2(h0, h1);
    m = make_uint2(m0, m1);
}

// 8 w-values (two float4) -> hi/mid short8 frags of v=-2*w (exact pow2 scale);
// bit-identical to the retired prep tables (same split2 on same values).
__device__ __forceinline__ void build8n2(float4 a, float4 b, short8& hi, short8& mi) {
    union { unsigned d[4]; short8 s; } H, M;
    split2(__fmul_rn(-2.0f, a.x), __fmul_rn(-2.0f, a.y), H.d[0], M.d[0]);
    split2(__fmul_rn(-2.0f, a.z), __fmul_rn(-2.0f, a.w), H.d[1], M.d[1]);
    split2(__fmul_rn(-2.0f, b.x), __fmul_rn(-2.0f, b.y), H.d[2], M.d[2]);
    split2(__fmul_rn(-2.0f, b.z), __fmul_rn(-2.0f, b.w), H.d[3], M.d[3]);
    hi = H.s; mi = M.s;
}

// xor-32 merge of (min1,min2) pairs across lane halves.
__device__ __forceinline__ void merge32(unsigned& m1, unsigned& m2) {
#ifdef VQ_PLSWAP
    uintx2 s1 = __builtin_amdgcn_permlane32_swap(m1, m1, false, false);
    uintx2 s2 = __builtin_amdgcn_permlane32_swap(m2, m2, false, false);
    m2 = umin2(umin2(s2[0], s2[1]), umax2(s1[0], s1[1]));
    m1 = umin2(s1[0], s1[1]);
#else
    unsigned o1 = __shfl_xor((int)m1, 32);
    unsigned o2 = __shfl_xor((int)m2, 32);
    m2 = umin2(umin2(m2, o2), umax2(m1, o1));
    m1 = umin2(m1, o1);
#endif
}

// top-2 (min1,min2) of 16 keys, balanced tree
__device__ __forceinline__ void top2_16(const unsigned* k, unsigned& m1, unsigned& m2) {
    unsigned lo[8], hi[8];
#pragma unroll
    for (int i = 0; i < 8; ++i) {
        lo[i] = umin2(k[2 * i], k[2 * i + 1]);
        hi[i] = umax2(k[2 * i], k[2 * i + 1]);
    }
#pragma unroll
    for (int s = 4; s >= 1; s >>= 1) {
#pragma unroll
        for (int i = 0; i < s; ++i) {
            unsigned l = umin2(lo[i], lo[i + s]);
            unsigned h = umin2(umax2(lo[i], lo[i + s]), umin2(hi[i], hi[i + s]));
            lo[i] = l; hi[i] = h;
        }
    }
    m1 = lo[0]; m2 = hi[0];
}

// ---- phase-1: 2048 blocks of 256 thr = 4 waves. Block = (row-tile of 256) x
// (codebook half of 256 cw), R11 mapping (half=bid&1). Prep folded in:
// A-frags + w2p3s built in-register from w (bit-identical values, R12
// absmax-0 verified). Per-wave math identical to R9/R11 (55.7-57us). ----
__launch_bounds__(256, 4)
__global__ void vq_gemm(const float* __restrict__ x,
                        const float* __restrict__ w,
                        uint2* __restrict__ mmg,
                        unsigned* __restrict__ cnt,
                        float* __restrict__ loss) {
    const int tid = threadIdx.x;
    const int bid = blockIdx.x;
    if (bid == 0 && tid == 0) { *cnt = 0u; *loss = 0.0f; }

    const int wave = tid >> 6, lane = tid & 63;
    const int row32 = lane & 31;   // A: cw-in-tile; B: x-row; C: x-row (col)
    const int khalf = lane >> 5;   // A/B: k-subwindow; C: cw-subset offset/4
    const int half = bid & 1;      // R11 mapping (proven)
    const int r0 = (bid >> 1) * 256;

    __shared__ float w2p3s[256];                         // 1 KB (this half)
    __shared__ __align__(16) unsigned sbh[2][32 * 36];   // B hi tiles (9 KB)
    __shared__ __align__(16) unsigned sbm[2][32 * 36];   // B mid tiles (9 KB)
    __shared__ uint2 mm[4][8][32];                       // per-wave min1/min2 (8 KB)

    // w2p3 in-register (streaming, numpy order => bit-identical to old prep)
    w2p3s[tid] = __fadd_rn(np_sumsq64_stream(w + (size_t)(half * 256 + tid) * DDIM), 3.0f);

    // A-frags in-register: tile tt (32 cw), k-step t (16 dims). Lane holds
    // cw = half*256 + wave*64 + tt*32 + row32, dims t*16 + khalf*8 + j.
    short8 ah[2][4], am[2][4];
#pragma unroll
    for (int tt = 0; tt < 2; ++tt) {
        const size_t cw = (size_t)(half * 256 + wave * 64 + tt * 32 + row32);
#pragma unroll
        for (int t = 0; t < 4; ++t) {
            const float* wp = w + cw * 64 + t * 16 + khalf * 8;
            float4 a = *(const float4*)wp;
            float4 b = *(const float4*)(wp + 4);
            build8n2(a, b, ah[tt][t], am[tt][t]);
        }
    }

    // staging: 256 threads stage 32 rows x 16 float4: thread owns rows srow,
    // srow+16 at float4-col sc4.
    const int srow = tid >> 4, sc4 = tid & 15;
    {
        float4 v0 = *(const float4*)(x + (size_t)(r0 + srow) * DDIM + 4 * sc4);
        float4 v1 = *(const float4*)(x + (size_t)(r0 + srow + 16) * DDIM + 4 * sc4);
        uint2 h, m;
        split4(v0, h, m);
        *(uint2*)&sbh[0][srow * 36 + 2 * sc4] = h;
        *(uint2*)&sbm[0][srow * 36 + 2 * sc4] = m;
        split4(v1, h, m);
        *(uint2*)&sbh[0][(srow + 16) * 36 + 2 * sc4] = h;
        *(uint2*)&sbm[0][(srow + 16) * 36 + 2 * sc4] = m;
    }
    __syncthreads();

    // key cw base for this lane's C-subset: + tt*32 + (reg&3)+8*(reg>>2)
    const unsigned cwk = (unsigned)(half * 256 + wave * 64 + 4 * khalf);

    for (int it = 0; it < 8; ++it) {
        const int p = it & 1;
        float4 pre0, pre1;
        if (it < 7) {
            pre0 = *(const float4*)(x + (size_t)(r0 + (it + 1) * 32 + srow) * DDIM + 4 * sc4);
            pre1 = *(const float4*)(x + (size_t)(r0 + (it + 1) * 32 + srow + 16) * DDIM + 4 * sc4);
        }

        // B-frags: row = row32, k-step t: dwords t*8 + khalf*4 .. +3
        short8 bh[4], bm[4];
#pragma unroll
        for (int t = 0; t < 4; ++t) {
            bh[t] = *(const short8*)&sbh[p][row32 * 36 + t * 8 + khalf * 4];
            bm[t] = *(const short8*)&sbm[p][row32 * 36 + t * 8 + khalf * 4];
        }

        unsigned r1t[2], r2t[2];
#pragma unroll
        for (int tt = 0; tt < 2; ++tt) {
            // acc init: reg 4g+i -> m = i + 8g + 4*khalf (contiguous quads)
            floatx16 acc;
            const int wb = wave * 64 + tt * 32 + 4 * khalf;
#pragma unroll
            for (int g = 0; g < 4; ++g) {
                floatx4 v = *(const floatx4*)&w2p3s[wb + 8 * g];
                acc[4 * g + 0] = v[0]; acc[4 * g + 1] = v[1];
                acc[4 * g + 2] = v[2]; acc[4 * g + 3] = v[3];
            }
#pragma unroll
            for (int t = 0; t < 4; ++t) {
                acc = __builtin_amdgcn_mfma_f32_32x32x16_bf16(ah[tt][t], bh[t], acc, 0, 0, 0);
                acc = __builtin_amdgcn_mfma_f32_32x32x16_bf16(ah[tt][t], bm[t], acc, 0, 0, 0);
                acc = __builtin_amdgcn_mfma_f32_32x32x16_bf16(am[tt][t], bh[t], acc, 0, 0, 0);
            }
            // keys for this tile's 16 lane-local cw
            unsigned keys[16];
#pragma unroll
            for (int r = 0; r < 16; ++r) {
                const unsigned moff = (unsigned)((r & 3) + 8 * (r >> 2) + tt * 32);
                keys[r] = (__float_as_uint(acc[r]) << 9) + cwk + moff;
            }
            top2_16(keys, r1t[tt], r2t[tt]);
        }
        unsigned m1 = umin2(r1t[0], r1t[1]);
        unsigned m2 = umin2(umax2(r1t[0], r1t[1]), umin2(r2t[0], r2t[1]));
        merge32(m1, m2);   // combine complementary cw subsets (same x-row)
        if (lane < 32) mm[wave][it][row32] = make_uint2(m1, m2);

        if (it < 7) {
            uint2 h, m;
            split4(pre0, h, m);
            *(uint2*)&sbh[p ^ 1][srow * 36 + 2 * sc4] = h;
            *(uint2*)&sbm[p ^ 1][srow * 36 + 2 * sc4] = m;
            split4(pre1, h, m);
            *(uint2*)&sbh[p ^ 1][(srow + 16) * 36 + 2 * sc4] = h;
            *(uint2*)&sbm[p ^ 1][(srow + 16) * 36 + 2 * sc4] = m;
        }
        __syncthreads();
    }

    // deferred cross-wave merge: thread tid owns row r0+tid (it=tid>>5, rl=tid&31)
    unsigned a1 = 0xFFFFFFFFu, a2 = 0xFFFFFFFFu;
#pragma unroll
    for (int wv = 0; wv < 4; ++wv) {
        uint2 v = mm[wv][tid >> 5][tid & 31];
        a2 = umin2(umin2(a2, v.y), umax2(a1, v.x));
        a1 = umin2(a1, v.x);
    }
    mmg[(size_t)half * NROWS + (r0 + tid)] = make_uint2(a1, a2);
}

// ---- cooperative tail: 256 blocks x 512 thr (1 block/CU — trivially
// co-resident). Phase M: merge halves -> idx + flag list (2 rows/thread).
// grid.sync. Phase R: VERBATIM R11 recheck (1 cw/thread, wl loaded once —
// the config that did NOT spill; R12's 2-pass variant spilled wl to scratch).
__launch_bounds__(512, 4)
__global__ void vq_tail(const float* __restrict__ x,
                        const float* __restrict__ w,
                        const uint2* __restrict__ mmg,
                        float* __restrict__ out_idx,
                        unsigned* __restrict__ cnt,
                        unsigned* __restrict__ list, int listcap) {
    cg::grid_group grid = cg::this_grid();
    const int tid = threadIdx.x;
    const int bid = blockIdx.x;
    const int lane = tid & 63;

    // ---- phase M: rows bid*1024 + c*512 + tid (same per-row algebra as R11) --
#pragma unroll
    for (int c = 0; c < 2; ++c) {
        const int row = bid * 1024 + c * 512 + tid;
        uint2 v0 = mmg[row];
        uint2 v1 = mmg[(size_t)NROWS + row];
        unsigned a1 = umin2(v0.x, v1.x);
        unsigned a2 = umin2(umax2(v0.x, v1.x), umin2(v0.y, v1.y));
        out_idx[row] = (float)(a1 & 511u);
        bool flag = (a2 - a1 < MARGKEY);
        unsigned long long mask = __ballot(flag);
        int nw = __popcll(mask);
        unsigned base = 0;
        if (lane == 0 && nw) base = atomicAdd(cnt, (unsigned)nw);
        base = (unsigned)__shfl((int)base, 0);
        if (flag) {
            unsigned pos = base + (unsigned)__popcll(mask & ((1ull << lane) - 1ull));
            if ((int)pos < listcap) list[pos] = (unsigned)row;
        }
    }
    __threadfence();
    grid.sync();

    // ---- phase R: exact recheck, R11-verbatim structure ----
    unsigned total = *cnt;
    if (total > (unsigned)listcap) total = (unsigned)listcap;
    const unsigned nb = (total + 15) >> 4;

    // this thread's codeword + its exact w2 (numpy order) — loaded ONCE
    float wl[64];
    {
        const float4* wp = (const float4*)(w + (size_t)tid * DDIM);
#pragma unroll
        for (int j = 0; j < 16; ++j) {
            float4 v = wp[j];
            wl[4 * j + 0] = v.x; wl[4 * j + 1] = v.y;
            wl[4 * j + 2] = v.z; wl[4 * j + 3] = v.w;
        }
    }
    const float w2l = np_sumsq64(wl);

    __shared__ float d2tile[16][KCB];   // 32 KB
    __shared__ int rowbuf[16];
    __shared__ float x2buf[16];

    for (unsigned batch = (unsigned)bid; batch < nb; batch += 256u) {
        if (tid < 16) {
            unsigned li = batch * 16 + (unsigned)tid;
            rowbuf[tid] = (li < total) ? (int)list[li] : -1;
        }
        __syncthreads();

        // x2 per row: 8 threads/row, numpy pairwise-8 order + exact shfl tree
        if (tid < 128) {
            const int rl = tid >> 3, j = tid & 7;
            int row = rowbuf[rl]; if (row < 0) row = 0;
            const float* xr = x + (size_t)row * DDIM;
            float a0 = xr[j];
            float r = __fmul_rn(a0, a0);
#pragma unroll
            for (int i = 1; i < 8; ++i) {
                float ai = xr[8 * i + j];
                r = __fadd_rn(r, __fmul_rn(ai, ai));
            }
            float s1 = __fadd_rn(r,  __shfl_xor(r, 1));
            float s2 = __fadd_rn(s1, __shfl_xor(s1, 2));
            float s4 = __fadd_rn(s2, __shfl_xor(s2, 4));
            if (j == 0) x2buf[rl] = s4;
        }
        __syncthreads();

        // exact chains: 4 rows in flight, block-uniform broadcast x loads
        for (int g = 0; g < 16; g += 4) {
            int ra = rowbuf[g + 0]; if (ra < 0) ra = 0;
            int rb = rowbuf[g + 1]; if (rb < 0) rb = 0;
            int rc = rowbuf[g + 2]; if (rc < 0) rc = 0;
            int rd = rowbuf[g + 3]; if (rd < 0) rd = 0;
            const float* xr0 = x + (size_t)ra * DDIM;
            const float* xr1 = x + (size_t)rb * DDIM;
            const float* xr2 = x + (size_t)rc * DDIM;
            const float* xr3 = x + (size_t)rd * DDIM;
            float m0 = 0.f, m1 = 0.f, m2 = 0.f, m3 = 0.f;
#pragma unroll
            for (int jb = 0; jb < 16; ++jb) {
                float4 a0 = *(const float4*)(xr0 + 4 * jb);
                float4 a1 = *(const float4*)(xr1 + 4 * jb);
                float4 a2 = *(const float4*)(xr2 + 4 * jb);
                float4 a3 = *(const float4*)(xr3 + 4 * jb);
                m0 = __fmaf_rn(a0.x, wl[4 * jb + 0], m0);
                m0 = __fmaf_rn(a0.y, wl[4 * jb + 1], m0);
                m0 = __fmaf_rn(a0.z, wl[4 * jb + 2], m0);
                m0 = __fmaf_rn(a0.w, wl[4 * jb + 3], m0);
                m1 = __fmaf_rn(a1.x, wl[4 * jb + 0], m1);
                m1 = __fmaf_rn(a1.y, wl[4 * jb + 1], m1);
                m1 = __fmaf_rn(a1.z, wl[4 * jb + 2], m1);
                m1 = __fmaf_rn(a1.w, wl[4 * jb + 3], m1);
                m2 = __fmaf_rn(a2.x, wl[4 * jb + 0], m2);
                m2 = __fmaf_rn(a2.y, wl[4 * jb + 1], m2);
                m2 = __fmaf_rn(a2.z, wl[4 * jb + 2], m2);
                m2 = __fmaf_rn(a2.w, wl[4 * jb + 3], m2);
                m3 = __fmaf_rn(a3.x, wl[4 * jb + 0], m3);
                m3 = __fmaf_rn(a3.y, wl[4 * jb + 1], m3);
                m3 = __fmaf_rn(a3.z, wl[4 * jb + 2], m3);
                m3 = __fmaf_rn(a3.w, wl[4 * jb + 3], m3);
            }
            float X0 = x2buf[g + 0], X1 = x2buf[g + 1];
            float X2 = x2buf[g + 2], X3 = x2buf[g + 3];
            d2tile[g + 0][tid] = __fadd_rn(__fsub_rn(X0, __fmul_rn(2.0f, m0)), w2l);
            d2tile[g + 1][tid] = __fadd_rn(__fsub_rn(X1, __fmul_rn(2.0f, m1)), w2l);
            d2tile[g + 2][tid] = __fadd_rn(__fsub_rn(X2, __fmul_rn(2.0f, m2)), w2l);
            d2tile[g + 3][tid] = __fadd_rn(__fsub_rn(X3, __fmul_rn(2.0f, m3)), w2l);
        }
        __syncthreads();

        // exact argmin per row: 32 threads/row, strict < first-min [R4-verified]
        {
            const int rl  = tid >> 5;
            const int sub = tid & 31;
            float bv = d2tile[rl][sub];
            int   bi = sub;
#pragma unroll
            for (int i = 1; i < 16; ++i) {
                int cc = sub + 32 * i;
                float v = d2tile[rl][cc];
                if (v < bv) { bv = v; bi = cc; }
            }
#pragma unroll
            for (int s = 1; s < 32; s <<= 1) {
                float ov = __shfl_xor(bv, s);
                int   oi = __shfl_xor(bi, s);
                if (ov < bv || (ov == bv && oi < bi)) { bv = ov; bi = oi; }
            }
            if (sub == 0 && rowbuf[rl] >= 0) out_idx[rowbuf[rl]] = (float)bi;
        }
        __syncthreads();
    }
}

// ---- epilogue: gather codeword, quantized_st = fl(x + fl(q-x)), loss.
// UNCHANGED (loss partial-sum structure is bit-critical). ----
__launch_bounds__(256)
__global__ void vq_epilogue(const float* __restrict__ x,
                            const float* __restrict__ w,
                            const float* __restrict__ out_idx_f,
                            float* __restrict__ out_q,
                            float* __restrict__ out_loss) {
    const int tid = threadIdx.x;
    const int r0  = blockIdx.x * 256;
    const int bidx = (int)out_idx_f[r0 + tid];   // coalesced idx load
    const float4* wq = (const float4*)(w + (size_t)bidx * DDIM);

    __shared__ float tile[128][65];   // 33.3 KB, +1 pad => conflict-minimal
    __shared__ float red[4];

    float ls = 0.0f;
#pragma unroll
    for (int ph = 0; ph < 2; ++ph) {
        const int rb = r0 + ph * 128;
        __syncthreads();   // prior store-phase reads done before overwrite
        // coalesced load: 128 rows x 16 float4 = 2048 float4; 8 per thread
#pragma unroll
        for (int i = 0; i < 8; ++i) {
            const int li = tid + 256 * i;            // linear float4 index
            const int row = li >> 4, c4 = li & 15;
            float4 v = *(const float4*)(x + (size_t)(rb + row) * DDIM + 4 * c4);
            *(float4*)&tile[row][4 * c4] = v;
        }
        __syncthreads();
        // compute: threads ph*128..ph*128+127 own their row (tid->row kept)
        if ((tid >> 7) == ph) {
            const int lr = tid & 127;
#pragma unroll
            for (int j = 0; j < 16; ++j) {
                float4 xv = *(const float4*)&tile[lr][4 * j];
                float4 wv = wq[j];
                float e0 = __fsub_rn(wv.x, xv.x), e1 = __fsub_rn(wv.y, xv.y);
                float e2 = __fsub_rn(wv.z, xv.z), e3 = __fsub_rn(wv.w, xv.w);
                ls = fmaf(e0, e0, ls); ls = fmaf(e1, e1, ls);
                ls = fmaf(e2, e2, ls); ls = fmaf(e3, e3, ls);
                float4 q;
                q.x = __fadd_rn(xv.x, e0); q.y = __fadd_rn(xv.y, e1);
                q.z = __fadd_rn(xv.z, e2); q.w = __fadd_rn(xv.w, e3);
                *(float4*)&tile[lr][4 * j] = q;   // own-row slot, in place
            }
        }
        __syncthreads();
        // coalesced store of q from LDS
#pragma unroll
        for (int i = 0; i < 8; ++i) {
            const int li = tid + 256 * i;
            const int row = li >> 4, c4 = li & 15;
            float4 qv = *(const float4*)&tile[row][4 * c4];
            *(float4*)(out_q + (size_t)(rb + row) * DDIM + 4 * c4) = qv;
        }
    }

#pragma unroll
    for (int off = 32; off > 0; off >>= 1) ls += __shfl_down(ls, off);
    const int lane = tid & 63;
    const int wid  = tid >> 6;
    if (lane == 0) red[wid] = ls;
    __syncthreads();
    if (tid == 0) {
        float t = (red[0] + red[1]) + (red[2] + red[3]);
        atomicAdd(out_loss, t * (1.25f / (float)(NROWS * DDIM)));  // (1+BETA)*mean
    }
}

extern "C" void kernel_launch(void* const* d_in, const int* in_sizes, int n_in,
                              void* d_out, int out_size, void* d_ws, size_t ws_size,
                              hipStream_t stream) {
    const float* x = (const float*)d_in[0];   // encoding [N, 64]
    const float* w = (const float*)d_in[1];   // weight   [512, 64]

    float* out      = (float*)d_out;
    float* out_idx  = out;
    float* out_q    = out + (size_t)NROWS;
    float* out_loss = out + (size_t)NROWS + (size_t)NROWS * DDIM;

    // half-results parked in the out_q region (4 MB of 64 MB); epilogue
    // rewrites out_q fully AFTER vq_tail's last read of mmg.
    uint2* mmg = (uint2*)out_q;

    char* ws = (char*)d_ws;
    unsigned* cnt  = (unsigned*)(ws + WS_CNT);
    unsigned* list = (unsigned*)(ws + WS_LIST);
    long cap = ((long)ws_size - WS_LIST) / 4;
    int listcap = cap > 0 ? (cap > NROWS ? NROWS : (int)cap) : 0;

    vq_gemm<<<2048, 256, 0, stream>>>(x, w, mmg, cnt, out_loss);

    {
        const float* xx = x; const float* ww = w;
        const uint2* mm = mmg; float* oi = out_idx;
        unsigned* cp = cnt; unsigned* lp = list; int lc = listcap;
        void* args[] = { &xx, &ww, &mm, &oi, &cp, &lp, &lc };
        hipLaunchCooperativeKernel((const void*)vq_tail, dim3(256), dim3(512),
                                   args, 0, stream);
    }

    vq_epilogue<<<NROWS / 256, 256, 0, stream>>>(x, w, out_idx, out_q, out_loss);
}

// Round 10
// 245.172 us; speedup vs baseline: 1.4110x; 1.2747x over previous
//
#include <hip/hip_runtime.h>

// VectorQuantizer: N=262144 rows, D=64 dims, K=512 codewords, fp32.
// out layout (floats): [0,N) idx ; [N, N+N*D) quantized_st ; [N+N*D] vq_loss
//
// CORRECTNESS MODEL (verified R2-R5, absmax 0): reference fp32 bit pattern is
//   d2 = fl(fl(x2 - fl(2*m)) + w2), x2/w2 numpy pairwise-8 order, m = sequential
//   FMA chain d ascending (BLAS), argmin strict < (first-min tie-break).
// Two-phase: MFMA approx scores (bf16 hi/mid splits of -2w, 3 terms) +
// exact-chain recheck of rows with top-2 gap < margin.
//
// R14: back to the fully-MEASURED R11 checkpoint (248.5us; gemm 57us) with
// ONE change: recheck's private wl[64] eliminated (R12/R13 showed VGPR=60-64
// => the array spills/remats, putting scratch/L2 latency on the FMA critical
// path; R11's same-body recheck was likely silently slow too). Chains now
// load w per-jb as float4 (same values, same op order => d2 bits identical);
// w2l via np_sumsq64_stream (identical numpy order, absmax-0-verified);
// launch_bounds(512,2) for register headroom. Prep/gemm/merge/epilogue
// verbatim R11. 5 dispatches.
#define NROWS 262144
#define DDIM  64
#define KCB   512

// key = (fp32 bits of s''=w2+3-2*dot) << 9 | cw ; s'' in [2.8,3.2] => one
// exponent octave => bits monotone. 1 key unit = ulp(3)/512 ; MARGKEY = 3<<17
// => 768 ulps = 1.83e-4 >= 2x worst-case |approx - ref| bound (~9.1e-5).
#define MARGKEY (3u << 17)

// ws layout (bytes)
#define WS_CNT   0
#define WS_W2P3  1024
#define WS_WHI   4096
#define WS_WMID  69632
#define WS_LIST  135168

typedef __attribute__((ext_vector_type(8))) short short8;
typedef __attribute__((ext_vector_type(4))) float floatx4;
typedef __attribute__((ext_vector_type(16))) float floatx16;
typedef __attribute__((ext_vector_type(2))) unsigned int uintx2;

#if defined(__has_builtin)
#if __has_builtin(__builtin_amdgcn_permlane32_swap)
#define VQ_PLSWAP 1
#endif
#endif

__device__ __forceinline__ unsigned umin2(unsigned a, unsigned b) { return a < b ? a : b; }
__device__ __forceinline__ unsigned umax2(unsigned a, unsigned b) { return a > b ? a : b; }

// numpy FLOAT_pairwise_sum order for n=64 over terms fl(a[i]*a[i])  [R2-verified]
__device__ __forceinline__ float np_sumsq64(const float* a) {
    float r[8];
#pragma unroll
    for (int j = 0; j < 8; ++j) r[j] = __fmul_rn(a[j], a[j]);
#pragma unroll
    for (int i = 8; i < 64; i += 8) {
#pragma unroll
        for (int j = 0; j < 8; ++j)
            r[j] = __fadd_rn(r[j], __fmul_rn(a[i + j], a[i + j]));
    }
    return __fadd_rn(__fadd_rn(__fadd_rn(r[0], r[1]), __fadd_rn(r[2], r[3])),
                     __fadd_rn(__fadd_rn(r[4], r[5]), __fadd_rn(r[6], r[7])));
}

// streaming variant: identical op order via float4 loads (no private array);
// bit-identity vs np_sumsq64 verified in R12/R13 gemm (absmax 0).
__device__ __forceinline__ float np_sumsq64_stream(const float* a) {
    const float4* p = (const float4*)a;
    float4 v0 = p[0], v1 = p[1];
    float r[8];
    r[0] = __fmul_rn(v0.x, v0.x); r[1] = __fmul_rn(v0.y, v0.y);
    r[2] = __fmul_rn(v0.z, v0.z); r[3] = __fmul_rn(v0.w, v0.w);
    r[4] = __fmul_rn(v1.x, v1.x); r[5] = __fmul_rn(v1.y, v1.y);
    r[6] = __fmul_rn(v1.z, v1.z); r[7] = __fmul_rn(v1.w, v1.w);
#pragma unroll
    for (int i = 1; i < 8; ++i) {
        float4 u0 = p[2 * i], u1 = p[2 * i + 1];
        r[0] = __fadd_rn(r[0], __fmul_rn(u0.x, u0.x));
        r[1] = __fadd_rn(r[1], __fmul_rn(u0.y, u0.y));
        r[2] = __fadd_rn(r[2], __fmul_rn(u0.z, u0.z));
        r[3] = __fadd_rn(r[3], __fmul_rn(u0.w, u0.w));
        r[4] = __fadd_rn(r[4], __fmul_rn(u1.x, u1.x));
        r[5] = __fadd_rn(r[5], __fmul_rn(u1.y, u1.y));
        r[6] = __fadd_rn(r[6], __fmul_rn(u1.z, u1.z));
        r[7] = __fadd_rn(r[7], __fmul_rn(u1.w, u1.w));
    }
    return __fadd_rn(__fadd_rn(__fadd_rn(r[0], r[1]), __fadd_rn(r[2], r[3])),
                     __fadd_rn(__fadd_rn(r[4], r[5]), __fadd_rn(r[6], r[7])));
}

// pack two fp32 into bf16-truncate hi dword + residual-bf16 mid dword
__device__ __forceinline__ void split2(float e0, float e1, unsigned& hid, unsigned& mid) {
    unsigned u0 = __float_as_uint(e0), u1 = __float_as_uint(e1);
    float r0 = __fsub_rn(e0, __uint_as_float(u0 & 0xFFFF0000u));  // exact
    float r1 = __fsub_rn(e1, __uint_as_float(u1 & 0xFFFF0000u));  // exact
    hid = (u0 >> 16) | (u1 & 0xFFFF0000u);
    mid = (__float_as_uint(r0) >> 16) | (__float_as_uint(r1) & 0xFFFF0000u);
}

__device__ __forceinline__ void split4(float4 v, uint2& h, uint2& m) {
    unsigned h0, m0, h1, m1;
    split2(v.x, v.y, h0, m0);
    split2(v.z, v.w, h1, m1);
    h = make_uint2(h0, h1);
    m = make_uint2(m0, m1);
}

// xor-32 merge of (min1,min2) pairs across lane halves.
__device__ __forceinline__ void merge32(unsigned& m1, unsigned& m2) {
#ifdef VQ_PLSWAP
    uintx2 s1 = __builtin_amdgcn_permlane32_swap(m1, m1, false, false);
    uintx2 s2 = __builtin_amdgcn_permlane32_swap(m2, m2, false, false);
    m2 = umin2(umin2(s2[0], s2[1]), umax2(s1[0], s1[1]));
    m1 = umin2(s1[0], s1[1]);
#else
    unsigned o1 = __shfl_xor((int)m1, 32);
    unsigned o2 = __shfl_xor((int)m2, 32);
    m2 = umin2(umin2(m2, o2), umax2(m1, o1));
    m1 = umin2(m1, o1);
#endif
}

// top-2 (min1,min2) of 16 keys, balanced tree
__device__ __forceinline__ void top2_16(const unsigned* k, unsigned& m1, unsigned& m2) {
    unsigned lo[8], hi[8];
#pragma unroll
    for (int i = 0; i < 8; ++i) {
        lo[i] = umin2(k[2 * i], k[2 * i + 1]);
        hi[i] = umax2(k[2 * i], k[2 * i + 1]);
    }
#pragma unroll
    for (int s = 4; s >= 1; s >>= 1) {
#pragma unroll
        for (int i = 0; i < s; ++i) {
            unsigned l = umin2(lo[i], lo[i + s]);
            unsigned h = umin2(umax2(lo[i], lo[i + s]), umin2(hi[i], hi[i + s]));
            lo[i] = l; hi[i] = h;
        }
    }
    m1 = lo[0]; m2 = hi[0];
}

// ---- prep: w2p3 = fl(w2)+3, bf16 truncated splits of v = -2*w; zeroes
// cnt/loss (replaces memsets). Bit-identical tables to R5. [R11-verbatim] ----
__global__ void vq_prep(const float* __restrict__ w, float* __restrict__ w2p3,
                        unsigned short* __restrict__ whi,
                        unsigned short* __restrict__ wmid,
                        unsigned* __restrict__ cnt, float* __restrict__ loss) {
    const int k = blockIdx.x * blockDim.x + threadIdx.x;  // 0..511
    if (k == 0) { *cnt = 0u; *loss = 0.0f; }
    float ws[64];
    const float4* wp = (const float4*)(w + (size_t)k * DDIM);
#pragma unroll
    for (int j = 0; j < 16; ++j) {
        float4 v = wp[j];
        ws[4 * j + 0] = v.x; ws[4 * j + 1] = v.y;
        ws[4 * j + 2] = v.z; ws[4 * j + 3] = v.w;
    }
    w2p3[k] = __fadd_rn(np_sumsq64(ws), 3.0f);
#pragma unroll
    for (int j = 0; j < 8; ++j) {
        union { unsigned d[4]; short8 s; } H, M;
#pragma unroll
        for (int t = 0; t < 4; ++t) {
            float v0 = __fmul_rn(-2.0f, ws[8 * j + 2 * t]);      // exact (pow2)
            float v1 = __fmul_rn(-2.0f, ws[8 * j + 2 * t + 1]);  // exact (pow2)
            split2(v0, v1, H.d[t], M.d[t]);
        }
        *(short8*)(whi  + (size_t)k * 64 + 8 * j) = H.s;
        *(short8*)(wmid + (size_t)k * 64 + 8 * j) = M.s;
    }
}

// ---- phase-1: 2048 blocks of 256 thr = 4 waves. Block = (row-tile of 256) x
// (codebook half of 256 cw). Wave owns 64 cw = 2x 32x32x16 cw-tiles; 32
// rows/iter double-buffered LDS staging. Per lane: one x-row (col=lane&31),
// 32 cw values -> lane-local top-2 -> single merge32. [R11-verbatim, 57us] ----
__launch_bounds__(256, 4)
__global__ void vq_gemm(const float* __restrict__ x,
                        const unsigned short* __restrict__ whi,
                        const unsigned short* __restrict__ wmid,
                        const float* __restrict__ w2p3g,
                        uint2* __restrict__ mmg) {
    const int tid = threadIdx.x;
    const int wave = tid >> 6, lane = tid & 63;
    const int row32 = lane & 31;   // A: cw-in-tile; B: x-row; C: x-row (col)
    const int khalf = lane >> 5;   // A/B: k-subwindow; C: cw-subset offset/4
    const int half = blockIdx.x & 1;
    const int r0 = (blockIdx.x >> 1) * 256;

    __shared__ float w2p3s[256];                         // 1 KB (this half)
    __shared__ __align__(16) unsigned sbh[2][32 * 36];   // B hi tiles (9 KB)
    __shared__ __align__(16) unsigned sbm[2][32 * 36];   // B mid tiles (9 KB)
    __shared__ uint2 mm[4][8][32];                       // per-wave min1/min2 (8 KB)

    w2p3s[tid] = w2p3g[half * 256 + tid];

    // A-frags: tile tt (32 cw), k-step t (16 dims). Lane holds
    // cw = half*256 + wave*64 + tt*32 + row32, dims t*16 + khalf*8 + j.
    short8 ah[2][4], am[2][4];
#pragma unroll
    for (int tt = 0; tt < 2; ++tt) {
        const size_t cw = (size_t)(half * 256 + wave * 64 + tt * 32 + row32);
#pragma unroll
        for (int t = 0; t < 4; ++t) {
            const size_t off = cw * 64 + t * 16 + khalf * 8;
            ah[tt][t] = *(const short8*)(whi + off);
            am[tt][t] = *(const short8*)(wmid + off);
        }
    }

    // staging: 256 threads stage 32 rows x 16 float4: thread owns rows srow,
    // srow+16 at float4-col sc4.
    const int srow = tid >> 4, sc4 = tid & 15;
    {
        float4 v0 = *(const float4*)(x + (size_t)(r0 + srow) * DDIM + 4 * sc4);
        float4 v1 = *(const float4*)(x + (size_t)(r0 + srow + 16) * DDIM + 4 * sc4);
        uint2 h, m;
        split4(v0, h, m);
        *(uint2*)&sbh[0][srow * 36 + 2 * sc4] = h;
        *(uint2*)&sbm[0][srow * 36 + 2 * sc4] = m;
        split4(v1, h, m);
        *(uint2*)&sbh[0][(srow + 16) * 36 + 2 * sc4] = h;
        *(uint2*)&sbm[0][(srow + 16) * 36 + 2 * sc4] = m;
    }
    __syncthreads();

    // key cw base for this lane's C-subset: + tt*32 + (reg&3)+8*(reg>>2)
    const unsigned cwk = (unsigned)(half * 256 + wave * 64 + 4 * khalf);

    for (int it = 0; it < 8; ++it) {
        const int p = it & 1;
        float4 pre0, pre1;
        if (it < 7) {
            pre0 = *(const float4*)(x + (size_t)(r0 + (it + 1) * 32 + srow) * DDIM + 4 * sc4);
            pre1 = *(const float4*)(x + (size_t)(r0 + (it + 1) * 32 + srow + 16) * DDIM + 4 * sc4);
        }

        // B-frags: row = row32, k-step t: dwords t*8 + khalf*4 .. +3
        short8 bh[4], bm[4];
#pragma unroll
        for (int t = 0; t < 4; ++t) {
            bh[t] = *(const short8*)&sbh[p][row32 * 36 + t * 8 + khalf * 4];
            bm[t] = *(const short8*)&sbm[p][row32 * 36 + t * 8 + khalf * 4];
        }

        unsigned r1t[2], r2t[2];
#pragma unroll
        for (int tt = 0; tt < 2; ++tt) {
            // acc init: reg 4g+i -> m = i + 8g + 4*khalf (contiguous quads)
            floatx16 acc;
            const int wb = wave * 64 + tt * 32 + 4 * khalf;
#pragma unroll
            for (int g = 0; g < 4; ++g) {
                floatx4 v = *(const floatx4*)&w2p3s[wb + 8 * g];
                acc[4 * g + 0] = v[0]; acc[4 * g + 1] = v[1];
                acc[4 * g + 2] = v[2]; acc[4 * g + 3] = v[3];
            }
#pragma unroll
            for (int t = 0; t < 4; ++t) {
                acc = __builtin_amdgcn_mfma_f32_32x32x16_bf16(ah[tt][t], bh[t], acc, 0, 0, 0);
                acc = __builtin_amdgcn_mfma_f32_32x32x16_bf16(ah[tt][t], bm[t], acc, 0, 0, 0);
                acc = __builtin_amdgcn_mfma_f32_32x32x16_bf16(am[tt][t], bh[t], acc, 0, 0, 0);
            }
            // keys for this tile's 16 lane-local cw
            unsigned keys[16];
#pragma unroll
            for (int r = 0; r < 16; ++r) {
                const unsigned moff = (unsigned)((r & 3) + 8 * (r >> 2) + tt * 32);
                keys[r] = (__float_as_uint(acc[r]) << 9) + cwk + moff;
            }
            top2_16(keys, r1t[tt], r2t[tt]);
        }
        unsigned m1 = umin2(r1t[0], r1t[1]);
        unsigned m2 = umin2(umax2(r1t[0], r1t[1]), umin2(r2t[0], r2t[1]));
        merge32(m1, m2);   // combine complementary cw subsets (same x-row)
        if (lane < 32) mm[wave][it][row32] = make_uint2(m1, m2);

        if (it < 7) {
            uint2 h, m;
            split4(pre0, h, m);
            *(uint2*)&sbh[p ^ 1][srow * 36 + 2 * sc4] = h;
            *(uint2*)&sbm[p ^ 1][srow * 36 + 2 * sc4] = m;
            split4(pre1, h, m);
            *(uint2*)&sbh[p ^ 1][(srow + 16) * 36 + 2 * sc4] = h;
            *(uint2*)&sbm[p ^ 1][(srow + 16) * 36 + 2 * sc4] = m;
        }
        __syncthreads();
    }

    // deferred cross-wave merge: thread tid owns row r0+tid (it=tid>>5, rl=tid&31)
    unsigned a1 = 0xFFFFFFFFu, a2 = 0xFFFFFFFFu;
#pragma unroll
    for (int wv = 0; wv < 4; ++wv) {
        uint2 v = mm[wv][tid >> 5][tid & 31];
        a2 = umin2(umin2(a2, v.y), umax2(a1, v.x));
        a1 = umin2(a1, v.x);
    }
    mmg[(size_t)half * NROWS + (r0 + tid)] = make_uint2(a1, a2);
}

// ---- merge halves: combine the two 256-cw top-2 results per row, write idx,
// flag rows with top-2 gap < margin into the recheck list. [R11-verbatim] ----
__launch_bounds__(256)
__global__ void vq_merge(const uint2* __restrict__ mmg,
                         float* __restrict__ out_idx,
                         unsigned* __restrict__ cnt,
                         unsigned* __restrict__ list, int listcap) {
    const int row = blockIdx.x * 256 + threadIdx.x;
    const int lane = threadIdx.x & 63;
    uint2 v0 = mmg[row];
    uint2 v1 = mmg[(size_t)NROWS + row];
    unsigned a1 = umin2(v0.x, v1.x);
    unsigned a2 = umin2(umax2(v0.x, v1.x), umin2(v0.y, v1.y));
    out_idx[row] = (float)(a1 & 511u);
    bool flag = (a2 - a1 < MARGKEY);
    unsigned long long mask = __ballot(flag);
    int nw = __popcll(mask);
    unsigned base = 0;
    if (lane == 0 && nw) base = atomicAdd(cnt, (unsigned)nw);
    base = (unsigned)__shfl((int)base, 0);
    if (flag) {
        unsigned pos = base + (unsigned)__popcll(mask & ((1ull << lane) - 1ull));
        if ((int)pos < listcap) list[pos] = (unsigned)row;
    }
}

// ---- recheck: R14 — no private wl[64] (R12/R13 proved it spills: VGPR 60-64,
// scratch/L2 latency on the FMA path). w loaded per-jb as float4 (same values,
// same chain order => d2 bits identical); w2l via stream variant (identical
// numpy order). launch_bounds(512,2) = VGPR cap 256, nothing spills. ----
__launch_bounds__(512, 2)
__global__ void vq_recheck(const float* __restrict__ x,
                           const float* __restrict__ w,
                           const unsigned* __restrict__ cnt,
                           const unsigned* __restrict__ list, int listcap,
                           float* __restrict__ out_idx) {
    const int tid = threadIdx.x;
    unsigned total = *cnt;
    if (total > (unsigned)listcap) total = (unsigned)listcap;
    const unsigned nb = (total + 15) >> 4;
    if (blockIdx.x >= nb) return;   // early out (uniform)

    // this thread's codeword row pointer + exact w2 (numpy order, streaming)
    const float4* wp = (const float4*)(w + (size_t)tid * DDIM);
    const float w2l = np_sumsq64_stream(w + (size_t)tid * DDIM);

    __shared__ float d2tile[16][KCB];   // 32 KB
    __shared__ int rowbuf[16];
    __shared__ float x2buf[16];

    for (unsigned batch = blockIdx.x; batch < nb; batch += gridDim.x) {
        if (tid < 16) {
            unsigned li = batch * 16 + (unsigned)tid;
            rowbuf[tid] = (li < total) ? (int)list[li] : -1;
        }
        __syncthreads();

        // x2 per row: 8 threads/row, numpy pairwise-8 order + exact shfl tree
        if (tid < 128) {
            const int rl = tid >> 3, j = tid & 7;
            int row = rowbuf[rl]; if (row < 0) row = 0;
            const float* xr = x + (size_t)row * DDIM;
            float a0 = xr[j];
            float r = __fmul_rn(a0, a0);
#pragma unroll
            for (int i = 1; i < 8; ++i) {
                float ai = xr[8 * i + j];
                r = __fadd_rn(r, __fmul_rn(ai, ai));
            }
            float s1 = __fadd_rn(r,  __shfl_xor(r, 1));
            float s2 = __fadd_rn(s1, __shfl_xor(s1, 2));
            float s4 = __fadd_rn(s2, __shfl_xor(s2, 4));
            if (j == 0) x2buf[rl] = s4;
        }
        __syncthreads();

        // exact chains: 4 rows in flight; w loaded per-jb (float4), same
        // chain order as R4/R11 => bit-identical d2
        for (int g = 0; g < 16; g += 4) {
            int ra = rowbuf[g + 0]; if (ra < 0) ra = 0;
            int rb = rowbuf[g + 1]; if (rb < 0) rb = 0;
            int rc = rowbuf[g + 2]; if (rc < 0) rc = 0;
            int rd = rowbuf[g + 3]; if (rd < 0) rd = 0;
            const float* xr0 = x + (size_t)ra * DDIM;
            const float* xr1 = x + (size_t)rb * DDIM;
            const float* xr2 = x + (size_t)rc * DDIM;
            const float* xr3 = x + (size_t)rd * DDIM;
            float m0 = 0.f, m1 = 0.f, m2 = 0.f, m3 = 0.f;
#pragma unroll
            for (int jb = 0; jb < 16; ++jb) {
                float4 wv = wp[jb];
                float4 a0 = *(const float4*)(xr0 + 4 * jb);
                float4 a1 = *(const float4*)(xr1 + 4 * jb);
                float4 a2 = *(const float4*)(xr2 + 4 * jb);
                float4 a3 = *(const float4*)(xr3 + 4 * jb);
                m0 = __fmaf_rn(a0.x, wv.x, m0);
                m0 = __fmaf_rn(a0.y, wv.y, m0);
                m0 = __fmaf_rn(a0.z, wv.z, m0);
                m0 = __fmaf_rn(a0.w, wv.w, m0);
                m1 = __fmaf_rn(a1.x, wv.x, m1);
                m1 = __fmaf_rn(a1.y, wv.y, m1);
                m1 = __fmaf_rn(a1.z, wv.z, m1);
                m1 = __fmaf_rn(a1.w, wv.w, m1);
                m2 = __fmaf_rn(a2.x, wv.x, m2);
                m2 = __fmaf_rn(a2.y, wv.y, m2);
                m2 = __fmaf_rn(a2.z, wv.z, m2);
                m2 = __fmaf_rn(a2.w, wv.w, m2);
                m3 = __fmaf_rn(a3.x, wv.x, m3);
                m3 = __fmaf_rn(a3.y, wv.y, m3);
                m3 = __fmaf_rn(a3.z, wv.z, m3);
                m3 = __fmaf_rn(a3.w, wv.w, m3);
            }
            float X0 = x2buf[g + 0], X1 = x2buf[g + 1];
            float X2 = x2buf[g + 2], X3 = x2buf[g + 3];
            d2tile[g + 0][tid] = __fadd_rn(__fsub_rn(X0, __fmul_rn(2.0f, m0)), w2l);
            d2tile[g + 1][tid] = __fadd_rn(__fsub_rn(X1, __fmul_rn(2.0f, m1)), w2l);
            d2tile[g + 2][tid] = __fadd_rn(__fsub_rn(X2, __fmul_rn(2.0f, m2)), w2l);
            d2tile[g + 3][tid] = __fadd_rn(__fsub_rn(X3, __fmul_rn(2.0f, m3)), w2l);
        }
        __syncthreads();

        // exact argmin per row: 32 threads/row, strict < first-min [R4-verified]
        {
            const int rl  = tid >> 5;
            const int sub = tid & 31;
            float bv = d2tile[rl][sub];
            int   bi = sub;
#pragma unroll
            for (int i = 1; i < 16; ++i) {
                int cc = sub + 32 * i;
                float v = d2tile[rl][cc];
                if (v < bv) { bv = v; bi = cc; }
            }
#pragma unroll
            for (int s = 1; s < 32; s <<= 1) {
                float ov = __shfl_xor(bv, s);
                int   oi = __shfl_xor(bi, s);
                if (ov < bv || (ov == bv && oi < bi)) { bv = ov; bi = oi; }
            }
            if (sub == 0 && rowbuf[rl] >= 0) out_idx[rowbuf[rl]] = (float)bi;
        }
        __syncthreads();
    }
}

// ---- epilogue: gather codeword, quantized_st = fl(x + fl(q-x)), loss.
// [R11-verbatim; loss partial-sum structure is bit-critical] ----
__launch_bounds__(256)
__global__ void vq_epilogue(const float* __restrict__ x,
                            const float* __restrict__ w,
                            const float* __restrict__ out_idx_f,
                            float* __restrict__ out_q,
                            float* __restrict__ out_loss) {
    const int tid = threadIdx.x;
    const int r0  = blockIdx.x * 256;
    const int bidx = (int)out_idx_f[r0 + tid];   // coalesced idx load
    const float4* wq = (const float4*)(w + (size_t)bidx * DDIM);

    __shared__ float tile[128][65];   // 33.3 KB, +1 pad => conflict-minimal
    __shared__ float red[4];

    float ls = 0.0f;
#pragma unroll
    for (int ph = 0; ph < 2; ++ph) {
        const int rb = r0 + ph * 128;
        __syncthreads();   // prior store-phase reads done before overwrite
        // coalesced load: 128 rows x 16 float4 = 2048 float4; 8 per thread
#pragma unroll
        for (int i = 0; i < 8; ++i) {
            const int li = tid + 256 * i;            // linear float4 index
            const int row = li >> 4, c4 = li & 15;
            float4 v = *(const float4*)(x + (size_t)(rb + row) * DDIM + 4 * c4);
            *(float4*)&tile[row][4 * c4] = v;
        }
        __syncthreads();
        // compute: threads ph*128..ph*128+127 own their row (tid->row kept)
        if ((tid >> 7) == ph) {
            const int lr = tid & 127;
#pragma unroll
            for (int j = 0; j < 16; ++j) {
                float4 xv = *(const float4*)&tile[lr][4 * j];
                float4 wv = wq[j];
                float e0 = __fsub_rn(wv.x, xv.x), e1 = __fsub_rn(wv.y, xv.y);
                float e2 = __fsub_rn(wv.z, xv.z), e3 = __fsub_rn(wv.w, xv.w);
                ls = fmaf(e0, e0, ls); ls = fmaf(e1, e1, ls);
                ls = fmaf(e2, e2, ls); ls = fmaf(e3, e3, ls);
                float4 q;
                q.x = __fadd_rn(xv.x, e0); q.y = __fadd_rn(xv.y, e1);
                q.z = __fadd_rn(xv.z, e2); q.w = __fadd_rn(xv.w, e3);
                *(float4*)&tile[lr][4 * j] = q;   // own-row slot, in place
            }
        }
        __syncthreads();
        // coalesced store of q from LDS
#pragma unroll
        for (int i = 0; i < 8; ++i) {
            const int li = tid + 256 * i;
            const int row = li >> 4, c4 = li & 15;
            float4 qv = *(const float4*)&tile[row][4 * c4];
            *(float4*)(out_q + (size_t)(rb + row) * DDIM + 4 * c4) = qv;
        }
    }

#pragma unroll
    for (int off = 32; off > 0; off >>= 1) ls += __shfl_down(ls, off);
    const int lane = tid & 63;
    const int wid  = tid >> 6;
    if (lane == 0) red[wid] = ls;
    __syncthreads();
    if (tid == 0) {
        float t = (red[0] + red[1]) + (red[2] + red[3]);
        atomicAdd(out_loss, t * (1.25f / (float)(NROWS * DDIM)));  // (1+BETA)*mean
    }
}

extern "C" void kernel_launch(void* const* d_in, const int* in_sizes, int n_in,
                              void* d_out, int out_size, void* d_ws, size_t ws_size,
                              hipStream_t stream) {
    const float* x = (const float*)d_in[0];   // encoding [N, 64]
    const float* w = (const float*)d_in[1];   // weight   [512, 64]

    float* out      = (float*)d_out;
    float* out_idx  = out;
    float* out_q    = out + (size_t)NROWS;
    float* out_loss = out + (size_t)NROWS + (size_t)NROWS * DDIM;

    // half-results parked in the out_q region (4 MB of 64 MB); epilogue
    // rewrites out_q fully AFTER vq_merge's last read of mmg.
    uint2* mmg = (uint2*)out_q;

    char* ws = (char*)d_ws;
    unsigned* cnt  = (unsigned*)(ws + WS_CNT);
    float* w2p3    = (float*)(ws + WS_W2P3);
    unsigned short* whi  = (unsigned short*)(ws + WS_WHI);
    unsigned short* wmid = (unsigned short*)(ws + WS_WMID);
    unsigned* list = (unsigned*)(ws + WS_LIST);
    long cap = ((long)ws_size - WS_LIST) / 4;
    int listcap = cap > 0 ? (cap > NROWS ? NROWS : (int)cap) : 0;

    vq_prep<<<2, 256, 0, stream>>>(w, w2p3, whi, wmid, cnt, out_loss);
    vq_gemm<<<2048, 256, 0, stream>>>(x, whi, wmid, w2p3, mmg);
    vq_merge<<<NROWS / 256, 256, 0, stream>>>(mmg, out_idx, cnt, list, listcap);
    vq_recheck<<<256, 512, 0, stream>>>(x, w, cnt, list, listcap, out_idx);
    vq_epilogue<<<NROWS / 256, 256, 0, stream>>>(x, w, out_idx, out_q, out_loss);
}

// Round 12
// 240.779 us; speedup vs baseline: 1.4368x; 1.0182x over previous
//
#include <hip/hip_runtime.h>

// VectorQuantizer: N=262144 rows, D=64 dims, K=512 codewords, fp32.
// out layout (floats): [0,N) idx ; [N, N+N*D) quantized_st ; [N+N*D] vq_loss
//
// CORRECTNESS MODEL (verified R2-R5, absmax 0): reference fp32 bit pattern is
//   d2 = fl(fl(x2 - fl(2*m)) + w2), x2/w2 numpy pairwise-8 order, m = sequential
//   FMA chain d ascending (BLAS), argmin strict < (first-min tie-break).
// Two-phase: MFMA approx scores (bf16 hi/mid splits of -2w, 3 terms) +
// exact-chain recheck of rows with top-2 gap < margin.
//
// R15 resubmit (R11-round bench was an infra failure — container failed to
// acquire; kernel never ran). Base: R14 = 245.2us, gemm 57.5.
// (a) epilogue restructure — single 256-row LDS tile (66.6KB, [256][65]:
//     load/store phases <=2-way bank aliasing = free; compute stride 65 == 1
//     mod 32 => conflict-free), coalesced load -> ALL threads compute own
//     row -> coalesced store; 2 barriers (was 6), no half-idle compute.
//     Thread->row mapping, fmaf chain, shfl tree, red[4], atomicAdd
//     unchanged => loss/q bit-identical.
// (b) prep spread to 8 blocks x 64 thr (same math, less latency-bound tail).
// gemm/merge/recheck verbatim R14.
#define NROWS 262144
#define DDIM  64
#define KCB   512

// key = (fp32 bits of s''=w2+3-2*dot) << 9 | cw ; s'' in [2.8,3.2] => one
// exponent octave => bits monotone. 1 key unit = ulp(3)/512 ; MARGKEY = 3<<17
// => 768 ulps = 1.83e-4 >= 2x worst-case |approx - ref| bound (~9.1e-5).
#define MARGKEY (3u << 17)

// ws layout (bytes)
#define WS_CNT   0
#define WS_W2P3  1024
#define WS_WHI   4096
#define WS_WMID  69632
#define WS_LIST  135168

typedef __attribute__((ext_vector_type(8))) short short8;
typedef __attribute__((ext_vector_type(4))) float floatx4;
typedef __attribute__((ext_vector_type(16))) float floatx16;
typedef __attribute__((ext_vector_type(2))) unsigned int uintx2;

#if defined(__has_builtin)
#if __has_builtin(__builtin_amdgcn_permlane32_swap)
#define VQ_PLSWAP 1
#endif
#endif

__device__ __forceinline__ unsigned umin2(unsigned a, unsigned b) { return a < b ? a : b; }
__device__ __forceinline__ unsigned umax2(unsigned a, unsigned b) { return a > b ? a : b; }

// numpy FLOAT_pairwise_sum order for n=64 over terms fl(a[i]*a[i])  [R2-verified]
__device__ __forceinline__ float np_sumsq64(const float* a) {
    float r[8];
#pragma unroll
    for (int j = 0; j < 8; ++j) r[j] = __fmul_rn(a[j], a[j]);
#pragma unroll
    for (int i = 8; i < 64; i += 8) {
#pragma unroll
        for (int j = 0; j < 8; ++j)
            r[j] = __fadd_rn(r[j], __fmul_rn(a[i + j], a[i + j]));
    }
    return __fadd_rn(__fadd_rn(__fadd_rn(r[0], r[1]), __fadd_rn(r[2], r[3])),
                     __fadd_rn(__fadd_rn(r[4], r[5]), __fadd_rn(r[6], r[7])));
}

// streaming variant: identical op order via float4 loads (no private array);
// bit-identity vs np_sumsq64 verified in R12/R13 gemm (absmax 0).
__device__ __forceinline__ float np_sumsq64_stream(const float* a) {
    const float4* p = (const float4*)a;
    float4 v0 = p[0], v1 = p[1];
    float r[8];
    r[0] = __fmul_rn(v0.x, v0.x); r[1] = __fmul_rn(v0.y, v0.y);
    r[2] = __fmul_rn(v0.z, v0.z); r[3] = __fmul_rn(v0.w, v0.w);
    r[4] = __fmul_rn(v1.x, v1.x); r[5] = __fmul_rn(v1.y, v1.y);
    r[6] = __fmul_rn(v1.z, v1.z); r[7] = __fmul_rn(v1.w, v1.w);
#pragma unroll
    for (int i = 1; i < 8; ++i) {
        float4 u0 = p[2 * i], u1 = p[2 * i + 1];
        r[0] = __fadd_rn(r[0], __fmul_rn(u0.x, u0.x));
        r[1] = __fadd_rn(r[1], __fmul_rn(u0.y, u0.y));
        r[2] = __fadd_rn(r[2], __fmul_rn(u0.z, u0.z));
        r[3] = __fadd_rn(r[3], __fmul_rn(u0.w, u0.w));
        r[4] = __fadd_rn(r[4], __fmul_rn(u1.x, u1.x));
        r[5] = __fadd_rn(r[5], __fmul_rn(u1.y, u1.y));
        r[6] = __fadd_rn(r[6], __fmul_rn(u1.z, u1.z));
        r[7] = __fadd_rn(r[7], __fmul_rn(u1.w, u1.w));
    }
    return __fadd_rn(__fadd_rn(__fadd_rn(r[0], r[1]), __fadd_rn(r[2], r[3])),
                     __fadd_rn(__fadd_rn(r[4], r[5]), __fadd_rn(r[6], r[7])));
}

// pack two fp32 into bf16-truncate hi dword + residual-bf16 mid dword
__device__ __forceinline__ void split2(float e0, float e1, unsigned& hid, unsigned& mid) {
    unsigned u0 = __float_as_uint(e0), u1 = __float_as_uint(e1);
    float r0 = __fsub_rn(e0, __uint_as_float(u0 & 0xFFFF0000u));  // exact
    float r1 = __fsub_rn(e1, __uint_as_float(u1 & 0xFFFF0000u));  // exact
    hid = (u0 >> 16) | (u1 & 0xFFFF0000u);
    mid = (__float_as_uint(r0) >> 16) | (__float_as_uint(r1) & 0xFFFF0000u);
}

__device__ __forceinline__ void split4(float4 v, uint2& h, uint2& m) {
    unsigned h0, m0, h1, m1;
    split2(v.x, v.y, h0, m0);
    split2(v.z, v.w, h1, m1);
    h = make_uint2(h0, h1);
    m = make_uint2(m0, m1);
}

// xor-32 merge of (min1,min2) pairs across lane halves.
__device__ __forceinline__ void merge32(unsigned& m1, unsigned& m2) {
#ifdef VQ_PLSWAP
    uintx2 s1 = __builtin_amdgcn_permlane32_swap(m1, m1, false, false);
    uintx2 s2 = __builtin_amdgcn_permlane32_swap(m2, m2, false, false);
    m2 = umin2(umin2(s2[0], s2[1]), umax2(s1[0], s1[1]));
    m1 = umin2(s1[0], s1[1]);
#else
    unsigned o1 = __shfl_xor((int)m1, 32);
    unsigned o2 = __shfl_xor((int)m2, 32);
    m2 = umin2(umin2(m2, o2), umax2(m1, o1));
    m1 = umin2(m1, o1);
#endif
}

// top-2 (min1,min2) of 16 keys, balanced tree
__device__ __forceinline__ void top2_16(const unsigned* k, unsigned& m1, unsigned& m2) {
    unsigned lo[8], hi[8];
#pragma unroll
    for (int i = 0; i < 8; ++i) {
        lo[i] = umin2(k[2 * i], k[2 * i + 1]);
        hi[i] = umax2(k[2 * i], k[2 * i + 1]);
    }
#pragma unroll
    for (int s = 4; s >= 1; s >>= 1) {
#pragma unroll
        for (int i = 0; i < s; ++i) {
            unsigned l = umin2(lo[i], lo[i + s]);
            unsigned h = umin2(umax2(lo[i], lo[i + s]), umin2(hi[i], hi[i + s]));
            lo[i] = l; hi[i] = h;
        }
    }
    m1 = lo[0]; m2 = hi[0];
}

// ---- prep: w2p3 = fl(w2)+3, bf16 truncated splits of v = -2*w; zeroes
// cnt/loss. Same per-k math as R5 tables (bit-identical); grid now 8x64 to
// engage 8 CUs (was 2 blocks => latency-bound tail). ----
__global__ void vq_prep(const float* __restrict__ w, float* __restrict__ w2p3,
                        unsigned short* __restrict__ whi,
                        unsigned short* __restrict__ wmid,
                        unsigned* __restrict__ cnt, float* __restrict__ loss) {
    const int k = blockIdx.x * blockDim.x + threadIdx.x;  // 0..511
    if (k == 0) { *cnt = 0u; *loss = 0.0f; }
    float ws[64];
    const float4* wp = (const float4*)(w + (size_t)k * DDIM);
#pragma unroll
    for (int j = 0; j < 16; ++j) {
        float4 v = wp[j];
        ws[4 * j + 0] = v.x; ws[4 * j + 1] = v.y;
        ws[4 * j + 2] = v.z; ws[4 * j + 3] = v.w;
    }
    w2p3[k] = __fadd_rn(np_sumsq64(ws), 3.0f);
#pragma unroll
    for (int j = 0; j < 8; ++j) {
        union { unsigned d[4]; short8 s; } H, M;
#pragma unroll
        for (int t = 0; t < 4; ++t) {
            float v0 = __fmul_rn(-2.0f, ws[8 * j + 2 * t]);      // exact (pow2)
            float v1 = __fmul_rn(-2.0f, ws[8 * j + 2 * t + 1]);  // exact (pow2)
            split2(v0, v1, H.d[t], M.d[t]);
        }
        *(short8*)(whi  + (size_t)k * 64 + 8 * j) = H.s;
        *(short8*)(wmid + (size_t)k * 64 + 8 * j) = M.s;
    }
}

// ---- phase-1: 2048 blocks of 256 thr = 4 waves. Block = (row-tile of 256) x
// (codebook half of 256 cw). Wave owns 64 cw = 2x 32x32x16 cw-tiles; 32
// rows/iter double-buffered LDS staging. Per lane: one x-row (col=lane&31),
// 32 cw values -> lane-local top-2 -> single merge32. [R11/R14-verbatim] ----
__launch_bounds__(256, 4)
__global__ void vq_gemm(const float* __restrict__ x,
                        const unsigned short* __restrict__ whi,
                        const unsigned short* __restrict__ wmid,
                        const float* __restrict__ w2p3g,
                        uint2* __restrict__ mmg) {
    const int tid = threadIdx.x;
    const int wave = tid >> 6, lane = tid & 63;
    const int row32 = lane & 31;   // A: cw-in-tile; B: x-row; C: x-row (col)
    const int khalf = lane >> 5;   // A/B: k-subwindow; C: cw-subset offset/4
    const int half = blockIdx.x & 1;
    const int r0 = (blockIdx.x >> 1) * 256;

    __shared__ float w2p3s[256];                         // 1 KB (this half)
    __shared__ __align__(16) unsigned sbh[2][32 * 36];   // B hi tiles (9 KB)
    __shared__ __align__(16) unsigned sbm[2][32 * 36];   // B mid tiles (9 KB)
    __shared__ uint2 mm[4][8][32];                       // per-wave min1/min2 (8 KB)

    w2p3s[tid] = w2p3g[half * 256 + tid];

    // A-frags: tile tt (32 cw), k-step t (16 dims). Lane holds
    // cw = half*256 + wave*64 + tt*32 + row32, dims t*16 + khalf*8 + j.
    short8 ah[2][4], am[2][4];
#pragma unroll
    for (int tt = 0; tt < 2; ++tt) {
        const size_t cw = (size_t)(half * 256 + wave * 64 + tt * 32 + row32);
#pragma unroll
        for (int t = 0; t < 4; ++t) {
            const size_t off = cw * 64 + t * 16 + khalf * 8;
            ah[tt][t] = *(const short8*)(whi + off);
            am[tt][t] = *(const short8*)(wmid + off);
        }
    }

    // staging: 256 threads stage 32 rows x 16 float4: thread owns rows srow,
    // srow+16 at float4-col sc4.
    const int srow = tid >> 4, sc4 = tid & 15;
    {
        float4 v0 = *(const float4*)(x + (size_t)(r0 + srow) * DDIM + 4 * sc4);
        float4 v1 = *(const float4*)(x + (size_t)(r0 + srow + 16) * DDIM + 4 * sc4);
        uint2 h, m;
        split4(v0, h, m);
        *(uint2*)&sbh[0][srow * 36 + 2 * sc4] = h;
        *(uint2*)&sbm[0][srow * 36 + 2 * sc4] = m;
        split4(v1, h, m);
        *(uint2*)&sbh[0][(srow + 16) * 36 + 2 * sc4] = h;
        *(uint2*)&sbm[0][(srow + 16) * 36 + 2 * sc4] = m;
    }
    __syncthreads();

    // key cw base for this lane's C-subset: + tt*32 + (reg&3)+8*(reg>>2)
    const unsigned cwk = (unsigned)(half * 256 + wave * 64 + 4 * khalf);

    for (int it = 0; it < 8; ++it) {
        const int p = it & 1;
        float4 pre0, pre1;
        if (it < 7) {
            pre0 = *(const float4*)(x + (size_t)(r0 + (it + 1) * 32 + srow) * DDIM + 4 * sc4);
            pre1 = *(const float4*)(x + (size_t)(r0 + (it + 1) * 32 + srow + 16) * DDIM + 4 * sc4);
        }

        // B-frags: row = row32, k-step t: dwords t*8 + khalf*4 .. +3
        short8 bh[4], bm[4];
#pragma unroll
        for (int t = 0; t < 4; ++t) {
            bh[t] = *(const short8*)&sbh[p][row32 * 36 + t * 8 + khalf * 4];
            bm[t] = *(const short8*)&sbm[p][row32 * 36 + t * 8 + khalf * 4];
        }

        unsigned r1t[2], r2t[2];
#pragma unroll
        for (int tt = 0; tt < 2; ++tt) {
            // acc init: reg 4g+i -> m = i + 8g + 4*khalf (contiguous quads)
            floatx16 acc;
            const int wb = wave * 64 + tt * 32 + 4 * khalf;
#pragma unroll
            for (int g = 0; g < 4; ++g) {
                floatx4 v = *(const floatx4*)&w2p3s[wb + 8 * g];
                acc[4 * g + 0] = v[0]; acc[4 * g + 1] = v[1];
                acc[4 * g + 2] = v[2]; acc[4 * g + 3] = v[3];
            }
#pragma unroll
            for (int t = 0; t < 4; ++t) {
                acc = __builtin_amdgcn_mfma_f32_32x32x16_bf16(ah[tt][t], bh[t], acc, 0, 0, 0);
                acc = __builtin_amdgcn_mfma_f32_32x32x16_bf16(ah[tt][t], bm[t], acc, 0, 0, 0);
                acc = __builtin_amdgcn_mfma_f32_32x32x16_bf16(am[tt][t], bh[t], acc, 0, 0, 0);
            }
            // keys for this tile's 16 lane-local cw
            unsigned keys[16];
#pragma unroll
            for (int r = 0; r < 16; ++r) {
                const unsigned moff = (unsigned)((r & 3) + 8 * (r >> 2) + tt * 32);
                keys[r] = (__float_as_uint(acc[r]) << 9) + cwk + moff;
            }
            top2_16(keys, r1t[tt], r2t[tt]);
        }
        unsigned m1 = umin2(r1t[0], r1t[1]);
        unsigned m2 = umin2(umax2(r1t[0], r1t[1]), umin2(r2t[0], r2t[1]));
        merge32(m1, m2);   // combine complementary cw subsets (same x-row)
        if (lane < 32) mm[wave][it][row32] = make_uint2(m1, m2);

        if (it < 7) {
            uint2 h, m;
            split4(pre0, h, m);
            *(uint2*)&sbh[p ^ 1][srow * 36 + 2 * sc4] = h;
            *(uint2*)&sbm[p ^ 1][srow * 36 + 2 * sc4] = m;
            split4(pre1, h, m);
            *(uint2*)&sbh[p ^ 1][(srow + 16) * 36 + 2 * sc4] = h;
            *(uint2*)&sbm[p ^ 1][(srow + 16) * 36 + 2 * sc4] = m;
        }
        __syncthreads();
    }

    // deferred cross-wave merge: thread tid owns row r0+tid (it=tid>>5, rl=tid&31)
    unsigned a1 = 0xFFFFFFFFu, a2 = 0xFFFFFFFFu;
#pragma unroll
    for (int wv = 0; wv < 4; ++wv) {
        uint2 v = mm[wv][tid >> 5][tid & 31];
        a2 = umin2(umin2(a2, v.y), umax2(a1, v.x));
        a1 = umin2(a1, v.x);
    }
    mmg[(size_t)half * NROWS + (r0 + tid)] = make_uint2(a1, a2);
}

// ---- merge halves: combine the two 256-cw top-2 results per row, write idx,
// flag rows with top-2 gap < margin into the recheck list. [R11-verbatim] ----
__launch_bounds__(256)
__global__ void vq_merge(const uint2* __restrict__ mmg,
                         float* __restrict__ out_idx,
                         unsigned* __restrict__ cnt,
                         unsigned* __restrict__ list, int listcap) {
    const int row = blockIdx.x * 256 + threadIdx.x;
    const int lane = threadIdx.x & 63;
    uint2 v0 = mmg[row];
    uint2 v1 = mmg[(size_t)NROWS + row];
    unsigned a1 = umin2(v0.x, v1.x);
    unsigned a2 = umin2(umax2(v0.x, v1.x), umin2(v0.y, v1.y));
    out_idx[row] = (float)(a1 & 511u);
    bool flag = (a2 - a1 < MARGKEY);
    unsigned long long mask = __ballot(flag);
    int nw = __popcll(mask);
    unsigned base = 0;
    if (lane == 0 && nw) base = atomicAdd(cnt, (unsigned)nw);
    base = (unsigned)__shfl((int)base, 0);
    if (flag) {
        unsigned pos = base + (unsigned)__popcll(mask & ((1ull << lane) - 1ull));
        if ((int)pos < listcap) list[pos] = (unsigned)row;
    }
}

// ---- recheck: R14 — no private wl[64] (it spills: R12/R13 VGPR 60-64).
// w loaded per-jb as float4 (same values, same chain order => d2 bits
// identical); w2l via stream variant. launch_bounds(512,2). [R14-verbatim] ----
__launch_bounds__(512, 2)
__global__ void vq_recheck(const float* __restrict__ x,
                           const float* __restrict__ w,
                           const unsigned* __restrict__ cnt,
                           const unsigned* __restrict__ list, int listcap,
                           float* __restrict__ out_idx) {
    const int tid = threadIdx.x;
    unsigned total = *cnt;
    if (total > (unsigned)listcap) total = (unsigned)listcap;
    const unsigned nb = (total + 15) >> 4;
    if (blockIdx.x >= nb) return;   // early out (uniform)

    // this thread's codeword row pointer + exact w2 (numpy order, streaming)
    const float4* wp = (const float4*)(w + (size_t)tid * DDIM);
    const float w2l = np_sumsq64_stream(w + (size_t)tid * DDIM);

    __shared__ float d2tile[16][KCB];   // 32 KB
    __shared__ int rowbuf[16];
    __shared__ float x2buf[16];

    for (unsigned batch = blockIdx.x; batch < nb; batch += gridDim.x) {
        if (tid < 16) {
            unsigned li = batch * 16 + (unsigned)tid;
            rowbuf[tid] = (li < total) ? (int)list[li] : -1;
        }
        __syncthreads();

        // x2 per row: 8 threads/row, numpy pairwise-8 order + exact shfl tree
        if (tid < 128) {
            const int rl = tid >> 3, j = tid & 7;
            int row = rowbuf[rl]; if (row < 0) row = 0;
            const float* xr = x + (size_t)row * DDIM;
            float a0 = xr[j];
            float r = __fmul_rn(a0, a0);
#pragma unroll
            for (int i = 1; i < 8; ++i) {
                float ai = xr[8 * i + j];
                r = __fadd_rn(r, __fmul_rn(ai, ai));
            }
            float s1 = __fadd_rn(r,  __shfl_xor(r, 1));
            float s2 = __fadd_rn(s1, __shfl_xor(s1, 2));
            float s4 = __fadd_rn(s2, __shfl_xor(s2, 4));
            if (j == 0) x2buf[rl] = s4;
        }
        __syncthreads();

        // exact chains: 4 rows in flight; w loaded per-jb (float4), same
        // chain order as R4/R11 => bit-identical d2
        for (int g = 0; g < 16; g += 4) {
            int ra = rowbuf[g + 0]; if (ra < 0) ra = 0;
            int rb = rowbuf[g + 1]; if (rb < 0) rb = 0;
            int rc = rowbuf[g + 2]; if (rc < 0) rc = 0;
            int rd = rowbuf[g + 3]; if (rd < 0) rd = 0;
            const float* xr0 = x + (size_t)ra * DDIM;
            const float* xr1 = x + (size_t)rb * DDIM;
            const float* xr2 = x + (size_t)rc * DDIM;
            const float* xr3 = x + (size_t)rd * DDIM;
            float m0 = 0.f, m1 = 0.f, m2 = 0.f, m3 = 0.f;
#pragma unroll
            for (int jb = 0; jb < 16; ++jb) {
                float4 wv = wp[jb];
                float4 a0 = *(const float4*)(xr0 + 4 * jb);
                float4 a1 = *(const float4*)(xr1 + 4 * jb);
                float4 a2 = *(const float4*)(xr2 + 4 * jb);
                float4 a3 = *(const float4*)(xr3 + 4 * jb);
                m0 = __fmaf_rn(a0.x, wv.x, m0);
                m0 = __fmaf_rn(a0.y, wv.y, m0);
                m0 = __fmaf_rn(a0.z, wv.z, m0);
                m0 = __fmaf_rn(a0.w, wv.w, m0);
                m1 = __fmaf_rn(a1.x, wv.x, m1);
                m1 = __fmaf_rn(a1.y, wv.y, m1);
                m1 = __fmaf_rn(a1.z, wv.z, m1);
                m1 = __fmaf_rn(a1.w, wv.w, m1);
                m2 = __fmaf_rn(a2.x, wv.x, m2);
                m2 = __fmaf_rn(a2.y, wv.y, m2);
                m2 = __fmaf_rn(a2.z, wv.z, m2);
                m2 = __fmaf_rn(a2.w, wv.w, m2);
                m3 = __fmaf_rn(a3.x, wv.x, m3);
                m3 = __fmaf_rn(a3.y, wv.y, m3);
                m3 = __fmaf_rn(a3.z, wv.z, m3);
                m3 = __fmaf_rn(a3.w, wv.w, m3);
            }
            float X0 = x2buf[g + 0], X1 = x2buf[g + 1];
            float X2 = x2buf[g + 2], X3 = x2buf[g + 3];
            d2tile[g + 0][tid] = __fadd_rn(__fsub_rn(X0, __fmul_rn(2.0f, m0)), w2l);
            d2tile[g + 1][tid] = __fadd_rn(__fsub_rn(X1, __fmul_rn(2.0f, m1)), w2l);
            d2tile[g + 2][tid] = __fadd_rn(__fsub_rn(X2, __fmul_rn(2.0f, m2)), w2l);
            d2tile[g + 3][tid] = __fadd_rn(__fsub_rn(X3, __fmul_rn(2.0f, m3)), w2l);
        }
        __syncthreads();

        // exact argmin per row: 32 threads/row, strict < first-min [R4-verified]
        {
            const int rl  = tid >> 5;
            const int sub = tid & 31;
            float bv = d2tile[rl][sub];
            int   bi = sub;
#pragma unroll
            for (int i = 1; i < 16; ++i) {
                int cc = sub + 32 * i;
                float v = d2tile[rl][cc];
                if (v < bv) { bv = v; bi = cc; }
            }
#pragma unroll
            for (int s = 1; s < 32; s <<= 1) {
                float ov = __shfl_xor(bv, s);
                int   oi = __shfl_xor(bi, s);
                if (ov < bv || (ov == bv && oi < bi)) { bv = ov; bi = oi; }
            }
            if (sub == 0 && rowbuf[rl] >= 0) out_idx[rowbuf[rl]] = (float)bi;
        }
        __syncthreads();
    }
}

// ---- epilogue: gather codeword, quantized_st = fl(x + fl(q-x)), loss.
// R15: single 256-row LDS tile (66.6KB), coalesced load -> all threads
// compute own row -> coalesced store; 2 barriers (was 6), no idle half.
// [256][65] pad: load/store phases 2-way bank aliasing (free, m136);
// compute phase stride 65 == 1 mod 32 => conflict-free. Thread tid -> row
// r0+tid mapping, fmaf chain order, shfl tree, red[4], atomicAdd UNCHANGED
// => loss and q bit-identical to R11/R14. ----
__launch_bounds__(256)
__global__ void vq_epilogue(const float* __restrict__ x,
                            const float* __restrict__ w,
                            const float* __restrict__ out_idx_f,
                            float* __restrict__ out_q,
                            float* __restrict__ out_loss) {
    const int tid = threadIdx.x;
    const int r0  = blockIdx.x * 256;
    const int bidx = (int)out_idx_f[r0 + tid];   // coalesced idx load
    const float4* wq = (const float4*)(w + (size_t)bidx * DDIM);

    __shared__ float tile[256][65];   // 66.6 KB
    __shared__ float red[4];

    // coalesced load: 256 rows x 16 float4 = 4096 float4; 16 per thread
#pragma unroll
    for (int i = 0; i < 16; ++i) {
        const int li = tid + 256 * i;            // linear float4 index
        const int row = li >> 4, c4 = li & 15;
        float4 v = *(const float4*)(x + (size_t)(r0 + row) * DDIM + 4 * c4);
        *(float4*)&tile[row][4 * c4] = v;
    }
    __syncthreads();

    // compute: thread tid owns row r0+tid (mapping preserved)
    float ls = 0.0f;
#pragma unroll
    for (int j = 0; j < 16; ++j) {
        float4 xv = *(const float4*)&tile[tid][4 * j];
        float4 wv = wq[j];
        float e0 = __fsub_rn(wv.x, xv.x), e1 = __fsub_rn(wv.y, xv.y);
        float e2 = __fsub_rn(wv.z, xv.z), e3 = __fsub_rn(wv.w, xv.w);
        ls = fmaf(e0, e0, ls); ls = fmaf(e1, e1, ls);
        ls = fmaf(e2, e2, ls); ls = fmaf(e3, e3, ls);
        float4 q;
        q.x = __fadd_rn(xv.x, e0); q.y = __fadd_rn(xv.y, e1);
        q.z = __fadd_rn(xv.z, e2); q.w = __fadd_rn(xv.w, e3);
        *(float4*)&tile[tid][4 * j] = q;   // own-row slot, in place
    }
    __syncthreads();

    // coalesced store of q from LDS
#pragma unroll
    for (int i = 0; i < 16; ++i) {
        const int li = tid + 256 * i;
        const int row = li >> 4, c4 = li & 15;
        float4 qv = *(const float4*)&tile[row][4 * c4];
        *(float4*)(out_q + (size_t)(r0 + row) * DDIM + 4 * c4) = qv;
    }

#pragma unroll
    for (int off = 32; off > 0; off >>= 1) ls += __shfl_down(ls, off);
    const int lane = tid & 63;
    const int wid  = tid >> 6;
    if (lane == 0) red[wid] = ls;
    __syncthreads();
    if (tid == 0) {
        float t = (red[0] + red[1]) + (red[2] + red[3]);
        atomicAdd(out_loss, t * (1.25f / (float)(NROWS * DDIM)));  // (1+BETA)*mean
    }
}

extern "C" void kernel_launch(void* const* d_in, const int* in_sizes, int n_in,
                              void* d_out, int out_size, void* d_ws, size_t ws_size,
                              hipStream_t stream) {
    const float* x = (const float*)d_in[0];   // encoding [N, 64]
    const float* w = (const float*)d_in[1];   // weight   [512, 64]

    float* out      = (float*)d_out;
    float* out_idx  = out;
    float* out_q    = out + (size_t)NROWS;
    float* out_loss = out + (size_t)NROWS + (size_t)NROWS * DDIM;

    // half-results parked in the out_q region (4 MB of 64 MB); epilogue
    // rewrites out_q fully AFTER vq_merge's last read of mmg.
    uint2* mmg = (uint2*)out_q;

    char* ws = (char*)d_ws;
    unsigned* cnt  = (unsigned*)(ws + WS_CNT);
    float* w2p3    = (float*)(ws + WS_W2P3);
    unsigned short* whi  = (unsigned short*)(ws + WS_WHI);
    unsigned short* wmid = (unsigned short*)(ws + WS_WMID);
    unsigned* list = (unsigned*)(ws + WS_LIST);
    long cap = ((long)ws_size - WS_LIST) / 4;
    int listcap = cap > 0 ? (cap > NROWS ? NROWS : (int)cap) : 0;

    vq_prep<<<8, 64, 0, stream>>>(w, w2p3, whi, wmid, cnt, out_loss);
    vq_gemm<<<2048, 256, 0, stream>>>(x, whi, wmid, w2p3, mmg);
    vq_merge<<<NROWS / 256, 256, 0, stream>>>(mmg, out_idx, cnt, list, listcap);
    vq_recheck<<<256, 512, 0, stream>>>(x, w, cnt, list, listcap, out_idx);
    vq_epilogue<<<NROWS / 256, 256, 0, stream>>>(x, w, out_idx, out_q, out_loss);
}